// Round 2
// baseline (635.922 us; speedup 1.0000x reference)
//
#include <hip/hip_runtime.h>

// DOFEN inference fused pipeline — fp32 I/O (reference dtypes are float32).
// Shapes: B=1024, NCOL=NCOND=64, NRODT=1024, D=4, NEST=128, NFOREST=100,
//         NHID=128, NCLASS=10.

#define B_      1024
#define NCOL_   64
#define NCOND_  64
#define NRODT_  1024
#define D_      4
#define NEST_   128
#define NFOREST_ 100
#define NHID_   128
#define NCLASS_ 10
#define EPS_    1e-5f

// ---------------------------------------------------------------------------
// Kernel 1: per-(b,g) rODT weight.  phi1 sigmoid -> perm gather -> GN(4) ->
// 4x4 grouped conv -> ReLU -> GN(4) -> 4x1 conv.  One thread per (b,g).
// ---------------------------------------------------------------------------
__global__ __launch_bounds__(256) void k_rodt(
    const float* __restrict__ x,    const float* __restrict__ w1,
    const float* __restrict__ b1,   const int*  __restrict__ perm,
    const float* __restrict__ gn1g, const float* __restrict__ gn1b,
    const float* __restrict__ w2a,  const float* __restrict__ b2a,
    const float* __restrict__ gn2g, const float* __restrict__ gn2b,
    const float* __restrict__ w2b,  const float* __restrict__ b2b,
    float* __restrict__ wout)
{
    int idx = blockIdx.x * 256 + threadIdx.x;   // 0 .. B*NRODT-1
    int b = idx >> 10;
    int g = idx & (NRODT_ - 1);

    float v[4];
#pragma unroll
    for (int j = 0; j < 4; ++j) {
        int p    = perm[g * 4 + j];      // index into (cond*64 + col) space
        int col  = p & 63;
        int cond = p >> 6;
        float t = x[b * NCOL_ + col] * w1[col * NCOND_ + cond]
                + b1[col * NCOND_ + cond];
        v[j] = 1.0f / (1.0f + expf(-t)); // sigmoid
    }
    // GroupNorm over the 4 elements
    float mu = (v[0] + v[1] + v[2] + v[3]) * 0.25f;
    float var = 0.f;
#pragma unroll
    for (int j = 0; j < 4; ++j) { float d = v[j] - mu; var += d * d; }
    var *= 0.25f;
    float rs = rsqrtf(var + EPS_);
    float h[4];
#pragma unroll
    for (int j = 0; j < 4; ++j)
        h[j] = (v[j] - mu) * rs * gn1g[g * 4 + j] + gn1b[g * 4 + j];

    // grouped conv D->D + ReLU
    float t2[4];
#pragma unroll
    for (int o = 0; o < 4; ++o) {
        float a = b2a[g * 4 + o];
#pragma unroll
        for (int i = 0; i < 4; ++i)
            a += h[i] * w2a[g * 16 + i * 4 + o];
        t2[o] = fmaxf(a, 0.f);
    }
    // GroupNorm 2
    float mu2 = (t2[0] + t2[1] + t2[2] + t2[3]) * 0.25f;
    float var2 = 0.f;
#pragma unroll
    for (int j = 0; j < 4; ++j) { float d = t2[j] - mu2; var2 += d * d; }
    var2 *= 0.25f;
    float rs2 = rsqrtf(var2 + EPS_);

    // grouped conv D->1
    float wv = b2b[g];
#pragma unroll
    for (int i = 0; i < 4; ++i) {
        float hh = (t2[i] - mu2) * rs2 * gn2g[g * 4 + i] + gn2b[g * 4 + i];
        wv += hh * w2b[g * 4 + i];
    }
    wout[idx] = wv;
}

// ---------------------------------------------------------------------------
// Kernel 2: per-(b,f) forest + bagging MLP.  128 threads/block (2 waves).
// softmax(w[b, swr[f,:]]) -> F = ws @ E[swr[f,:],:] -> LN -> lin1+ReLU -> LN
// -> lin2 partial -> atomicAdd into fp32 accumulator (mean applied later).
// ---------------------------------------------------------------------------
__device__ __forceinline__ float blk_sum(float v, float* red, int tid)
{
#pragma unroll
    for (int o = 32; o; o >>= 1) v += __shfl_xor(v, o, 64);
    __syncthreads();                       // guard previous red readers
    if ((tid & 63) == 0) red[tid >> 6] = v;
    __syncthreads();
    return red[0] + red[1];
}

__device__ __forceinline__ float blk_max(float v, float* red, int tid)
{
#pragma unroll
    for (int o = 32; o; o >>= 1) v = fmaxf(v, __shfl_xor(v, o, 64));
    __syncthreads();
    if ((tid & 63) == 0) red[tid >> 6] = v;
    __syncthreads();
    return fmaxf(red[0], red[1]);
}

__global__ __launch_bounds__(128) void k_forest(
    const float* __restrict__ wv,   const int*  __restrict__ swr,
    const float* __restrict__ E,
    const float* __restrict__ ln1g,  const float* __restrict__ ln1b,
    const float* __restrict__ lin1w, const float* __restrict__ lin1b,
    const float* __restrict__ ln2g,  const float* __restrict__ ln2b,
    const float* __restrict__ lin2w, float* __restrict__ acc)
{
    __shared__ float ws_sh[NEST_];
    __shared__ int   r_sh[NEST_];
    __shared__ float zsh[NHID_];
    __shared__ float red[2];

    int tid = threadIdx.x;
    int b = blockIdx.x / NFOREST_;
    int f = blockIdx.x - b * NFOREST_;

    int   r = swr[f * NEST_ + tid];
    float w = wv[b * NRODT_ + r];

    // softmax over the 128 estimators
    float m  = blk_max(w, red, tid);
    float ex = expf(w - m);
    float s  = blk_sum(ex, red, tid);
    ws_sh[tid] = ex / s;
    r_sh[tid]  = r;
    __syncthreads();

    // F[h] = sum_e ws[e] * E[r_e, h]   (h = tid; coalesced 512B row reads)
    float F = 0.f;
#pragma unroll 8
    for (int e = 0; e < NEST_; ++e)
        F += ws_sh[e] * E[r_sh[e] * NHID_ + tid];

    // LayerNorm 1
    float mu  = blk_sum(F, red, tid) * (1.f / NHID_);
    float d   = F - mu;
    float var = blk_sum(d * d, red, tid) * (1.f / NHID_);
    float z   = d * rsqrtf(var + EPS_) * ln1g[tid] + ln1b[tid];
    zsh[tid] = z;
    __syncthreads();

    // lin1 (128x128) + ReLU
    float a = lin1b[tid];
#pragma unroll 8
    for (int k = 0; k < NHID_; ++k)
        a += zsh[k] * lin1w[k * NHID_ + tid];
    a = fmaxf(a, 0.f);

    // LayerNorm 2
    float mu2  = blk_sum(a, red, tid) * (1.f / NHID_);
    float d2   = a - mu2;
    float var2 = blk_sum(d2 * d2, red, tid) * (1.f / NHID_);
    float z2   = d2 * rsqrtf(var2 + EPS_) * ln2g[tid] + ln2b[tid];
    __syncthreads();           // all zsh readers done before overwrite
    zsh[tid] = z2;
    __syncthreads();

    // lin2 (128x10), bias deferred to final kernel
    if (tid < NCLASS_) {
        float a2 = 0.f;
#pragma unroll 8
        for (int k = 0; k < NHID_; ++k)
            a2 += zsh[k] * lin2w[k * NCLASS_ + tid];
        atomicAdd(&acc[b * NCLASS_ + tid], a2);
    }
}

// ---------------------------------------------------------------------------
// Kernel 3: out = acc/NFOREST + lin2_b
// ---------------------------------------------------------------------------
__global__ __launch_bounds__(256) void k_final(
    const float* __restrict__ acc, const float* __restrict__ lin2b,
    float* __restrict__ out)
{
    int i = blockIdx.x * 256 + threadIdx.x;
    if (i < B_ * NCLASS_) {
        int c = i % NCLASS_;
        out[i] = acc[i] * (1.f / NFOREST_) + lin2b[c];
    }
}

// ---------------------------------------------------------------------------
extern "C" void kernel_launch(void* const* d_in, const int* in_sizes, int n_in,
                              void* d_out, int out_size, void* d_ws, size_t ws_size,
                              hipStream_t stream)
{
    const float* x     = (const float*)d_in[0];
    const float* w1    = (const float*)d_in[1];
    const float* b1    = (const float*)d_in[2];
    const int*   perm  = (const int*)  d_in[3];
    const float* gn1g  = (const float*)d_in[4];
    const float* gn1b  = (const float*)d_in[5];
    const float* w2a   = (const float*)d_in[6];
    const float* b2a   = (const float*)d_in[7];
    const float* gn2g  = (const float*)d_in[8];
    const float* gn2b  = (const float*)d_in[9];
    const float* w2b   = (const float*)d_in[10];
    const float* b2b   = (const float*)d_in[11];
    const float* E     = (const float*)d_in[12];
    const int*   swr   = (const int*)  d_in[13];
    const float* ln1g  = (const float*)d_in[14];
    const float* ln1b  = (const float*)d_in[15];
    const float* lin1w = (const float*)d_in[16];
    const float* lin1b = (const float*)d_in[17];
    const float* ln2g  = (const float*)d_in[18];
    const float* ln2b  = (const float*)d_in[19];
    const float* lin2w = (const float*)d_in[20];
    const float* lin2b = (const float*)d_in[21];

    float* w_ws = (float*)d_ws;                                   // B*NRODT fp32
    float* accp = (float*)((char*)d_ws + (size_t)B_ * NRODT_ * sizeof(float));

    hipMemsetAsync(accp, 0, (size_t)B_ * NCLASS_ * sizeof(float), stream);

    k_rodt<<<(B_ * NRODT_) / 256, 256, 0, stream>>>(
        x, w1, b1, perm, gn1g, gn1b, w2a, b2a, gn2g, gn2b, w2b, b2b, w_ws);

    k_forest<<<B_ * NFOREST_, 128, 0, stream>>>(
        w_ws, swr, E, ln1g, ln1b, lin1w, lin1b, ln2g, ln2b, lin2w, accp);

    k_final<<<(B_ * NCLASS_ + 255) / 256, 256, 0, stream>>>(
        accp, lin2b, (float*)d_out);
}

// Round 3
// 535.631 us; speedup vs baseline: 1.1872x; 1.1872x over previous
//
#include <hip/hip_runtime.h>

// DOFEN inference fused pipeline — fp32 I/O.
// Shapes: B=1024, NCOL=NCOND=64, NRODT=1024, D=4, NEST=128, NFOREST=100,
//         NHID=128, NCLASS=10.
//
// Round 3: k_forest restructured — one block = (forest f) x (4 batch rows).
// Thread (bl, hq) owns batch b0+bl and hidden quad h=4*hq..4*hq+3.
// Inner GEMM loops: 1 float4 global load + 1 broadcast LDS read + 4 FMA.
// All reductions (softmax/LN) are 32-lane shfl trees (no barriers).

#define B_      1024
#define NCOL_   64
#define NCOND_  64
#define NRODT_  1024
#define D_      4
#define NEST_   128
#define NFOREST_ 100
#define NHID_   128
#define NCLASS_ 10
#define EPS_    1e-5f
#define BT_     4          // batch rows per block

// ---------------------------------------------------------------------------
// Kernel 1: per-(b,g) rODT weight (unchanged from round 2; ~45 us).
// ---------------------------------------------------------------------------
__global__ __launch_bounds__(256) void k_rodt(
    const float* __restrict__ x,    const float* __restrict__ w1,
    const float* __restrict__ b1,   const int*  __restrict__ perm,
    const float* __restrict__ gn1g, const float* __restrict__ gn1b,
    const float* __restrict__ w2a,  const float* __restrict__ b2a,
    const float* __restrict__ gn2g, const float* __restrict__ gn2b,
    const float* __restrict__ w2b,  const float* __restrict__ b2b,
    float* __restrict__ wout)
{
    int idx = blockIdx.x * 256 + threadIdx.x;   // 0 .. B*NRODT-1
    int b = idx >> 10;
    int g = idx & (NRODT_ - 1);

    float v[4];
#pragma unroll
    for (int j = 0; j < 4; ++j) {
        int p    = perm[g * 4 + j];
        int col  = p & 63;
        int cond = p >> 6;
        float t = x[b * NCOL_ + col] * w1[col * NCOND_ + cond]
                + b1[col * NCOND_ + cond];
        v[j] = 1.0f / (1.0f + expf(-t));
    }
    float mu = (v[0] + v[1] + v[2] + v[3]) * 0.25f;
    float var = 0.f;
#pragma unroll
    for (int j = 0; j < 4; ++j) { float d = v[j] - mu; var += d * d; }
    var *= 0.25f;
    float rs = rsqrtf(var + EPS_);
    float h[4];
#pragma unroll
    for (int j = 0; j < 4; ++j)
        h[j] = (v[j] - mu) * rs * gn1g[g * 4 + j] + gn1b[g * 4 + j];

    float t2[4];
#pragma unroll
    for (int o = 0; o < 4; ++o) {
        float a = b2a[g * 4 + o];
#pragma unroll
        for (int i = 0; i < 4; ++i)
            a += h[i] * w2a[g * 16 + i * 4 + o];
        t2[o] = fmaxf(a, 0.f);
    }
    float mu2 = (t2[0] + t2[1] + t2[2] + t2[3]) * 0.25f;
    float var2 = 0.f;
#pragma unroll
    for (int j = 0; j < 4; ++j) { float d = t2[j] - mu2; var2 += d * d; }
    var2 *= 0.25f;
    float rs2 = rsqrtf(var2 + EPS_);

    float wv = b2b[g];
#pragma unroll
    for (int i = 0; i < 4; ++i) {
        float hh = (t2[i] - mu2) * rs2 * gn2g[g * 4 + i] + gn2b[g * 4 + i];
        wv += hh * w2b[g * 4 + i];
    }
    wout[idx] = wv;
}

// ---------------------------------------------------------------------------
// 32-lane group reductions (lanes [g*32, g*32+31] of a wave; offsets <=16
// never cross the 32-lane boundary).
// ---------------------------------------------------------------------------
__device__ __forceinline__ float grp32_sum(float v)
{
#pragma unroll
    for (int o = 16; o; o >>= 1) v += __shfl_xor(v, o);
    return v;
}
__device__ __forceinline__ float grp32_max(float v)
{
#pragma unroll
    for (int o = 16; o; o >>= 1) v = fmaxf(v, __shfl_xor(v, o));
    return v;
}

// ---------------------------------------------------------------------------
// Kernel 2: block = (f, b0..b0+3).  128 threads: bl=tid>>5 (batch row),
// hq=tid&31 (hidden quad).
// ---------------------------------------------------------------------------
__global__ __launch_bounds__(128) void k_forest(
    const float* __restrict__ wv,    const int*  __restrict__ swr,
    const float* __restrict__ E,
    const float* __restrict__ ln1g,  const float* __restrict__ ln1b,
    const float* __restrict__ lin1w, const float* __restrict__ lin1b,
    const float* __restrict__ ln2g,  const float* __restrict__ ln2b,
    const float* __restrict__ lin2w, float* __restrict__ acc)
{
    __shared__ int   r_sh[NEST_];
    __shared__ __align__(16) float ws_sh[BT_][NEST_];
    __shared__ __align__(16) float zsh[BT_][NHID_];

    int tid = threadIdx.x;
    int bl  = tid >> 5;          // 0..3
    int hq  = tid & 31;          // hidden quad index
    int f   = blockIdx.x / (B_ / BT_);
    int bt  = blockIdx.x - f * (B_ / BT_);
    int b   = bt * BT_ + bl;

    r_sh[tid] = swr[f * NEST_ + tid];
    __syncthreads();

    // ---- softmax over 128 estimators for this thread's batch row ----
    float w0[4];
#pragma unroll
    for (int j = 0; j < 4; ++j)
        w0[j] = wv[b * NRODT_ + r_sh[hq + 32 * j]];
    float m = grp32_max(fmaxf(fmaxf(w0[0], w0[1]), fmaxf(w0[2], w0[3])));
    float ex[4], s = 0.f;
#pragma unroll
    for (int j = 0; j < 4; ++j) { ex[j] = expf(w0[j] - m); s += ex[j]; }
    s = grp32_sum(s);
    float inv = 1.f / s;
#pragma unroll
    for (int j = 0; j < 4; ++j)
        ws_sh[bl][hq + 32 * j] = ex[j] * inv;
    __syncthreads();

    // ---- F[b, 4hq..4hq+3] = sum_e ws[e] * E[r_e, :] ----
    const float4* E4 = (const float4*)E;
    float4 F = make_float4(0.f, 0.f, 0.f, 0.f);
#pragma unroll 4
    for (int e = 0; e < NEST_; ++e) {
        float4 Ev = E4[r_sh[e] * (NHID_ / 4) + hq];
        float  wsv = ws_sh[bl][e];
        F.x += wsv * Ev.x; F.y += wsv * Ev.y;
        F.z += wsv * Ev.z; F.w += wsv * Ev.w;
    }

    // ---- LayerNorm 1 (reduce over 128 h = this 32-lane group) ----
    float mu  = grp32_sum(F.x + F.y + F.z + F.w) * (1.f / NHID_);
    float dx = F.x - mu, dy = F.y - mu, dz = F.z - mu, dw = F.w - mu;
    float var = grp32_sum(dx * dx + dy * dy + dz * dz + dw * dw) * (1.f / NHID_);
    float rs  = rsqrtf(var + EPS_);
    float4 g1 = ((const float4*)ln1g)[hq];
    float4 o1 = ((const float4*)ln1b)[hq];
    float4 z;
    z.x = dx * rs * g1.x + o1.x;  z.y = dy * rs * g1.y + o1.y;
    z.z = dz * rs * g1.z + o1.z;  z.w = dw * rs * g1.w + o1.w;
    ((float4*)zsh[bl])[hq] = z;
    __syncthreads();

    // ---- lin1 (128x128) + ReLU ----
    const float4* W14 = (const float4*)lin1w;
    float4 a4 = ((const float4*)lin1b)[hq];
#pragma unroll 4
    for (int k = 0; k < NHID_; ++k) {
        float  zv = zsh[bl][k];
        float4 Wv = W14[k * (NHID_ / 4) + hq];
        a4.x += zv * Wv.x; a4.y += zv * Wv.y;
        a4.z += zv * Wv.z; a4.w += zv * Wv.w;
    }
    a4.x = fmaxf(a4.x, 0.f); a4.y = fmaxf(a4.y, 0.f);
    a4.z = fmaxf(a4.z, 0.f); a4.w = fmaxf(a4.w, 0.f);

    // ---- LayerNorm 2 ----
    float mu2  = grp32_sum(a4.x + a4.y + a4.z + a4.w) * (1.f / NHID_);
    float ex2  = a4.x - mu2, ey2 = a4.y - mu2, ez2 = a4.z - mu2, ew2 = a4.w - mu2;
    float var2 = grp32_sum(ex2 * ex2 + ey2 * ey2 + ez2 * ez2 + ew2 * ew2) * (1.f / NHID_);
    float rs2  = rsqrtf(var2 + EPS_);
    float4 g2 = ((const float4*)ln2g)[hq];
    float4 o2 = ((const float4*)ln2b)[hq];
    float4 z2;
    z2.x = ex2 * rs2 * g2.x + o2.x;  z2.y = ey2 * rs2 * g2.y + o2.y;
    z2.z = ez2 * rs2 * g2.z + o2.z;  z2.w = ew2 * rs2 * g2.w + o2.w;

    __syncthreads();                 // all lin1 readers of zsh done
    ((float4*)zsh[bl])[hq] = z2;
    __syncthreads();

    // ---- lin2 (128x10), bias deferred; atomic accumulate over forests ----
    if (hq < NCLASS_) {
        float a2 = 0.f;
#pragma unroll 4
        for (int k = 0; k < NHID_; ++k)
            a2 += zsh[bl][k] * lin2w[k * NCLASS_ + hq];
        atomicAdd(&acc[b * NCLASS_ + hq], a2);
    }
}

// ---------------------------------------------------------------------------
// Kernel 3: out = acc/NFOREST + lin2_b
// ---------------------------------------------------------------------------
__global__ __launch_bounds__(256) void k_final(
    const float* __restrict__ acc, const float* __restrict__ lin2b,
    float* __restrict__ out)
{
    int i = blockIdx.x * 256 + threadIdx.x;
    if (i < B_ * NCLASS_) {
        int c = i % NCLASS_;
        out[i] = acc[i] * (1.f / NFOREST_) + lin2b[c];
    }
}

// ---------------------------------------------------------------------------
extern "C" void kernel_launch(void* const* d_in, const int* in_sizes, int n_in,
                              void* d_out, int out_size, void* d_ws, size_t ws_size,
                              hipStream_t stream)
{
    const float* x     = (const float*)d_in[0];
    const float* w1    = (const float*)d_in[1];
    const float* b1    = (const float*)d_in[2];
    const int*   perm  = (const int*)  d_in[3];
    const float* gn1g  = (const float*)d_in[4];
    const float* gn1b  = (const float*)d_in[5];
    const float* w2a   = (const float*)d_in[6];
    const float* b2a   = (const float*)d_in[7];
    const float* gn2g  = (const float*)d_in[8];
    const float* gn2b  = (const float*)d_in[9];
    const float* w2b   = (const float*)d_in[10];
    const float* b2b   = (const float*)d_in[11];
    const float* E     = (const float*)d_in[12];
    const int*   swr   = (const int*)  d_in[13];
    const float* ln1g  = (const float*)d_in[14];
    const float* ln1b  = (const float*)d_in[15];
    const float* lin1w = (const float*)d_in[16];
    const float* lin1b = (const float*)d_in[17];
    const float* ln2g  = (const float*)d_in[18];
    const float* ln2b  = (const float*)d_in[19];
    const float* lin2w = (const float*)d_in[20];
    const float* lin2b = (const float*)d_in[21];

    float* w_ws = (float*)d_ws;                                   // B*NRODT fp32
    float* accp = (float*)((char*)d_ws + (size_t)B_ * NRODT_ * sizeof(float));

    hipMemsetAsync(accp, 0, (size_t)B_ * NCLASS_ * sizeof(float), stream);

    k_rodt<<<(B_ * NRODT_) / 256, 256, 0, stream>>>(
        x, w1, b1, perm, gn1g, gn1b, w2a, b2a, gn2g, gn2b, w2b, b2b, w_ws);

    k_forest<<<NFOREST_ * (B_ / BT_), 128, 0, stream>>>(
        w_ws, swr, E, ln1g, ln1b, lin1w, lin1b, ln2g, ln2b, lin2w, accp);

    k_final<<<(B_ * NCLASS_ + 255) / 256, 256, 0, stream>>>(
        accp, lin2b, (float*)d_out);
}

// Round 4
// 275.340 us; speedup vs baseline: 2.3096x; 1.9453x over previous
//
#include <hip/hip_runtime.h>

// DOFEN inference fused pipeline — fp32 I/O.
// Shapes: B=1024, NCOL=NCOND=64, NRODT=1024, D=4, NEST=128, NFOREST=100,
//         NHID=128, NCLASS=10.
//
// Round 4: k_forest register-blocked — block = (forest) x (16 batch rows),
// thread (rg,hq) owns 4 batch rows x hidden quad [4hq..4hq+3].
// Inner loops: 1 float4 global load + 1 broadcast ds_read_b128 + 16 FMA.
// ws/z packed as row-quads (in-thread 4x4 transpose); z quads bit-swizzled
// (q=(c<<5)|hq, k=((q&31)<<2)|(q>>5)) so writes are conflict-free and reads
// are broadcasts. Group-private LDS -> single barrier.

#define B_      1024
#define NCOL_   64
#define NCOND_  64
#define NRODT_  1024
#define D_      4
#define NEST_   128
#define NFOREST_ 100
#define NHID_   128
#define NCLASS_ 10
#define EPS_    1e-5f
#define RPT_    4                 // batch rows per thread
#define RPB_    16                // batch rows per block (4 groups x 4)

// ---------------------------------------------------------------------------
// 32-lane group reductions (offsets <=16 never cross the 32-lane boundary).
// ---------------------------------------------------------------------------
__device__ __forceinline__ float grp32_sum(float v)
{
#pragma unroll
    for (int o = 16; o; o >>= 1) v += __shfl_xor(v, o);
    return v;
}
__device__ __forceinline__ float grp32_max(float v)
{
#pragma unroll
    for (int o = 16; o; o >>= 1) v = fmaxf(v, __shfl_xor(v, o));
    return v;
}

// ---------------------------------------------------------------------------
// Kernel 1: per-(b,g) rODT weight.  Vectorized parameter loads.
// ---------------------------------------------------------------------------
__global__ __launch_bounds__(256) void k_rodt(
    const float* __restrict__ x,    const float* __restrict__ w1,
    const float* __restrict__ b1,   const int*  __restrict__ perm,
    const float* __restrict__ gn1g, const float* __restrict__ gn1b,
    const float* __restrict__ w2a,  const float* __restrict__ b2a,
    const float* __restrict__ gn2g, const float* __restrict__ gn2b,
    const float* __restrict__ w2b,  const float* __restrict__ b2b,
    float* __restrict__ wout)
{
    int idx = blockIdx.x * 256 + threadIdx.x;   // 0 .. B*NRODT-1
    int b = idx >> 10;
    int g = idx & (NRODT_ - 1);

    int4 p4 = ((const int4*)perm)[g];
    int pc[4] = { p4.x, p4.y, p4.z, p4.w };
    const float* xb = x + b * NCOL_;

    float v[4];
#pragma unroll
    for (int j = 0; j < 4; ++j) {
        int col  = pc[j] & 63;
        int cond = pc[j] >> 6;
        float t = xb[col] * w1[col * NCOND_ + cond] + b1[col * NCOND_ + cond];
        v[j] = 1.0f / (1.0f + expf(-t));
    }
    float mu = (v[0] + v[1] + v[2] + v[3]) * 0.25f;
    float var = 0.f;
#pragma unroll
    for (int j = 0; j < 4; ++j) { float d = v[j] - mu; var += d * d; }
    var *= 0.25f;
    float rs = rsqrtf(var + EPS_);

    float4 g1 = ((const float4*)gn1g)[g];
    float4 o1 = ((const float4*)gn1b)[g];
    float h[4];
    h[0] = (v[0] - mu) * rs * g1.x + o1.x;
    h[1] = (v[1] - mu) * rs * g1.y + o1.y;
    h[2] = (v[2] - mu) * rs * g1.z + o1.z;
    h[3] = (v[3] - mu) * rs * g1.w + o1.w;

    // grouped conv D->D + ReLU.  w2a4[g*4+i] = w2a[g][i][0..3] (over o)
    const float4* w2a4 = (const float4*)w2a;
    float4 a = ((const float4*)b2a)[g];
#pragma unroll
    for (int i = 0; i < 4; ++i) {
        float4 wv4 = w2a4[g * 4 + i];
        a.x += h[i] * wv4.x; a.y += h[i] * wv4.y;
        a.z += h[i] * wv4.z; a.w += h[i] * wv4.w;
    }
    float t2[4];
    t2[0] = fmaxf(a.x, 0.f); t2[1] = fmaxf(a.y, 0.f);
    t2[2] = fmaxf(a.z, 0.f); t2[3] = fmaxf(a.w, 0.f);

    float mu2 = (t2[0] + t2[1] + t2[2] + t2[3]) * 0.25f;
    float var2 = 0.f;
#pragma unroll
    for (int j = 0; j < 4; ++j) { float d = t2[j] - mu2; var2 += d * d; }
    var2 *= 0.25f;
    float rs2 = rsqrtf(var2 + EPS_);

    float4 g2  = ((const float4*)gn2g)[g];
    float4 o2  = ((const float4*)gn2b)[g];
    float4 wb4 = ((const float4*)w2b)[g];
    float wv = b2b[g];
    wv += ((t2[0] - mu2) * rs2 * g2.x + o2.x) * wb4.x;
    wv += ((t2[1] - mu2) * rs2 * g2.y + o2.y) * wb4.y;
    wv += ((t2[2] - mu2) * rs2 * g2.z + o2.z) * wb4.z;
    wv += ((t2[3] - mu2) * rs2 * g2.w + o2.w) * wb4.w;
    wout[idx] = wv;
}

// ---------------------------------------------------------------------------
// Kernel 2: block = (f, 16 batch rows).  128 threads: rg=tid>>5 (4 rows),
// hq=tid&31 (hidden quad 4hq..4hq+3).
// ---------------------------------------------------------------------------
__global__ __launch_bounds__(128) void k_forest(
    const float* __restrict__ wv,    const int*  __restrict__ swr,
    const float* __restrict__ E,
    const float* __restrict__ ln1g,  const float* __restrict__ ln1b,
    const float* __restrict__ lin1w, const float* __restrict__ lin1b,
    const float* __restrict__ ln2g,  const float* __restrict__ ln2b,
    const float* __restrict__ lin2w, float* __restrict__ acc)
{
    __shared__ int r_sh[NEST_];
    __shared__ __align__(16) float4 ws4[4][NEST_];   // [rg][e]     -> ws[rows0..3]
    __shared__ __align__(16) float4 zq4[4][NHID_];   // [rg][(c<<5)|hq] -> z[rows0..3][4hq+c]

    int tid = threadIdx.x;
    int rg  = tid >> 5;
    int hq  = tid & 31;
    int f   = blockIdx.x >> 6;                 // / (B_/RPB_) = /64
    int bt  = blockIdx.x & 63;
    int b0  = bt * RPB_ + rg * RPT_;           // this group's first batch row

    r_sh[tid] = swr[f * NEST_ + tid];
    __syncthreads();                           // only barrier in the kernel

    // ---- softmax over 128 estimators, 4 rows/thread ----
    float w0[RPT_][4];
#pragma unroll
    for (int j = 0; j < 4; ++j) {
        int r = r_sh[hq + 32 * j];
#pragma unroll
        for (int row = 0; row < RPT_; ++row)
            w0[row][j] = wv[(b0 + row) * NRODT_ + r];
    }
#pragma unroll
    for (int row = 0; row < RPT_; ++row) {
        float m = fmaxf(fmaxf(w0[row][0], w0[row][1]), fmaxf(w0[row][2], w0[row][3]));
        m = grp32_max(m);
        float s = 0.f;
#pragma unroll
        for (int j = 0; j < 4; ++j) { w0[row][j] = expf(w0[row][j] - m); s += w0[row][j]; }
        s = grp32_sum(s);
        float inv = 1.f / s;
#pragma unroll
        for (int j = 0; j < 4; ++j) w0[row][j] *= inv;
    }
#pragma unroll
    for (int j = 0; j < 4; ++j)     // quad e=hq+32j <- ws[rows 0..3]; conflict-free
        ws4[rg][hq + 32 * j] = make_float4(w0[0][j], w0[1][j], w0[2][j], w0[3][j]);

    // ---- F[rows][4hq..4hq+3] = sum_e ws[row][e] * E[r_e, :] ----
    const float4* E4 = (const float4*)E;
    float4 Fa[RPT_];
#pragma unroll
    for (int row = 0; row < RPT_; ++row) Fa[row] = make_float4(0.f, 0.f, 0.f, 0.f);
#pragma unroll 2
    for (int e = 0; e < NEST_; ++e) {
        float4 Ev = E4[r_sh[e] * (NHID_ / 4) + hq];
        float4 wq = ws4[rg][e];                // broadcast read
        Fa[0].x += wq.x * Ev.x; Fa[0].y += wq.x * Ev.y; Fa[0].z += wq.x * Ev.z; Fa[0].w += wq.x * Ev.w;
        Fa[1].x += wq.y * Ev.x; Fa[1].y += wq.y * Ev.y; Fa[1].z += wq.y * Ev.z; Fa[1].w += wq.y * Ev.w;
        Fa[2].x += wq.z * Ev.x; Fa[2].y += wq.z * Ev.y; Fa[2].z += wq.z * Ev.z; Fa[2].w += wq.z * Ev.w;
        Fa[3].x += wq.w * Ev.x; Fa[3].y += wq.w * Ev.y; Fa[3].z += wq.w * Ev.z; Fa[3].w += wq.w * Ev.w;
    }

    // ---- LayerNorm 1 per row; z -> zq4 (swizzled quads) ----
    float4 g1 = ((const float4*)ln1g)[hq];
    float4 o1 = ((const float4*)ln1b)[hq];
    float z[RPT_][4];
#pragma unroll
    for (int row = 0; row < RPT_; ++row) {
        float mu  = grp32_sum(Fa[row].x + Fa[row].y + Fa[row].z + Fa[row].w) * (1.f / NHID_);
        float dx = Fa[row].x - mu, dy = Fa[row].y - mu, dz = Fa[row].z - mu, dw = Fa[row].w - mu;
        float var = grp32_sum(dx * dx + dy * dy + dz * dz + dw * dw) * (1.f / NHID_);
        float rs  = rsqrtf(var + EPS_);
        z[row][0] = dx * rs * g1.x + o1.x;
        z[row][1] = dy * rs * g1.y + o1.y;
        z[row][2] = dz * rs * g1.z + o1.z;
        z[row][3] = dw * rs * g1.w + o1.w;
    }
#pragma unroll
    for (int c = 0; c < 4; ++c)     // quad (c<<5)|hq <- z[rows][4hq+c]; conflict-free
        zq4[rg][(c << 5) | hq] = make_float4(z[0][c], z[1][c], z[2][c], z[3][c]);

    // ---- lin1 (128x128) + ReLU ----
    const float4* W14 = (const float4*)lin1w;
    float4 bb = ((const float4*)lin1b)[hq];
    float4 a[RPT_];
#pragma unroll
    for (int row = 0; row < RPT_; ++row) a[row] = bb;
#pragma unroll 2
    for (int q = 0; q < NHID_; ++q) {
        int k = ((q & 31) << 2) | (q >> 5);    // swizzle inverse
        float4 zq = zq4[rg][q];                // broadcast: z[rows][k]
        float4 Wv = W14[k * (NHID_ / 4) + hq];
        a[0].x += zq.x * Wv.x; a[0].y += zq.x * Wv.y; a[0].z += zq.x * Wv.z; a[0].w += zq.x * Wv.w;
        a[1].x += zq.y * Wv.x; a[1].y += zq.y * Wv.y; a[1].z += zq.y * Wv.z; a[1].w += zq.y * Wv.w;
        a[2].x += zq.z * Wv.x; a[2].y += zq.z * Wv.y; a[2].z += zq.z * Wv.z; a[2].w += zq.z * Wv.w;
        a[3].x += zq.w * Wv.x; a[3].y += zq.w * Wv.y; a[3].z += zq.w * Wv.z; a[3].w += zq.w * Wv.w;
    }

    // ---- ReLU + LayerNorm 2 per row; z2 -> zq4 (overwrite, group-private) ----
    float4 g2 = ((const float4*)ln2g)[hq];
    float4 o2 = ((const float4*)ln2b)[hq];
#pragma unroll
    for (int row = 0; row < RPT_; ++row) {
        float ax = fmaxf(a[row].x, 0.f), ay = fmaxf(a[row].y, 0.f);
        float az = fmaxf(a[row].z, 0.f), aw = fmaxf(a[row].w, 0.f);
        float mu  = grp32_sum(ax + ay + az + aw) * (1.f / NHID_);
        float dx = ax - mu, dy = ay - mu, dz = az - mu, dw = aw - mu;
        float var = grp32_sum(dx * dx + dy * dy + dz * dz + dw * dw) * (1.f / NHID_);
        float rs  = rsqrtf(var + EPS_);
        z[row][0] = dx * rs * g2.x + o2.x;
        z[row][1] = dy * rs * g2.y + o2.y;
        z[row][2] = dz * rs * g2.z + o2.z;
        z[row][3] = dw * rs * g2.w + o2.w;
    }
#pragma unroll
    for (int c = 0; c < 4; ++c)
        zq4[rg][(c << 5) | hq] = make_float4(z[0][c], z[1][c], z[2][c], z[3][c]);

    // ---- lin2 (128x10): lanes 0..29 = (class, k-third); combine; atomics ----
    float p0 = 0.f, p1 = 0.f, p2 = 0.f, p3 = 0.f;
    if (hq < 30) {
        int part = hq / 10;
        int cls  = hq - part * 10;
        int qs = (part == 0) ? 0 : (part == 1 ? 43 : 86);
        int qe = (part == 0) ? 43 : (part == 1 ? 86 : 128);
        for (int q = qs; q < qe; ++q) {
            int k = ((q & 31) << 2) | (q >> 5);
            float4 zq = zq4[rg][q];
            float wl = lin2w[k * NCLASS_ + cls];
            p0 += zq.x * wl; p1 += zq.y * wl; p2 += zq.z * wl; p3 += zq.w * wl;
        }
    }
    p0 += __shfl_down(p0, 10) + __shfl_down(p0, 20);
    p1 += __shfl_down(p1, 10) + __shfl_down(p1, 20);
    p2 += __shfl_down(p2, 10) + __shfl_down(p2, 20);
    p3 += __shfl_down(p3, 10) + __shfl_down(p3, 20);
    if (hq < NCLASS_) {
        atomicAdd(&acc[(b0 + 0) * NCLASS_ + hq], p0);
        atomicAdd(&acc[(b0 + 1) * NCLASS_ + hq], p1);
        atomicAdd(&acc[(b0 + 2) * NCLASS_ + hq], p2);
        atomicAdd(&acc[(b0 + 3) * NCLASS_ + hq], p3);
    }
}

// ---------------------------------------------------------------------------
// Kernel 3: out = acc/NFOREST + lin2_b
// ---------------------------------------------------------------------------
__global__ __launch_bounds__(256) void k_final(
    const float* __restrict__ acc, const float* __restrict__ lin2b,
    float* __restrict__ out)
{
    int i = blockIdx.x * 256 + threadIdx.x;
    if (i < B_ * NCLASS_) {
        int c = i % NCLASS_;
        out[i] = acc[i] * (1.f / NFOREST_) + lin2b[c];
    }
}

// ---------------------------------------------------------------------------
extern "C" void kernel_launch(void* const* d_in, const int* in_sizes, int n_in,
                              void* d_out, int out_size, void* d_ws, size_t ws_size,
                              hipStream_t stream)
{
    const float* x     = (const float*)d_in[0];
    const float* w1    = (const float*)d_in[1];
    const float* b1    = (const float*)d_in[2];
    const int*   perm  = (const int*)  d_in[3];
    const float* gn1g  = (const float*)d_in[4];
    const float* gn1b  = (const float*)d_in[5];
    const float* w2a   = (const float*)d_in[6];
    const float* b2a   = (const float*)d_in[7];
    const float* gn2g  = (const float*)d_in[8];
    const float* gn2b  = (const float*)d_in[9];
    const float* w2b   = (const float*)d_in[10];
    const float* b2b   = (const float*)d_in[11];
    const float* E     = (const float*)d_in[12];
    const int*   swr   = (const int*)  d_in[13];
    const float* ln1g  = (const float*)d_in[14];
    const float* ln1b  = (const float*)d_in[15];
    const float* lin1w = (const float*)d_in[16];
    const float* lin1b = (const float*)d_in[17];
    const float* ln2g  = (const float*)d_in[18];
    const float* ln2b  = (const float*)d_in[19];
    const float* lin2w = (const float*)d_in[20];
    const float* lin2b = (const float*)d_in[21];

    float* w_ws = (float*)d_ws;                                   // B*NRODT fp32
    float* accp = (float*)((char*)d_ws + (size_t)B_ * NRODT_ * sizeof(float));

    hipMemsetAsync(accp, 0, (size_t)B_ * NCLASS_ * sizeof(float), stream);

    k_rodt<<<(B_ * NRODT_) / 256, 256, 0, stream>>>(
        x, w1, b1, perm, gn1g, gn1b, w2a, b2a, gn2g, gn2b, w2b, b2b, w_ws);

    k_forest<<<NFOREST_ * (B_ / RPB_), 128, 0, stream>>>(
        w_ws, swr, E, ln1g, ln1b, lin1w, lin1b, ln2g, ln2b, lin2w, accp);

    k_final<<<(B_ * NCLASS_ + 255) / 256, 256, 0, stream>>>(
        accp, lin2b, (float*)d_out);
}

// Round 5
// 268.525 us; speedup vs baseline: 2.3682x; 1.0254x over previous
//
#include <hip/hip_runtime.h>

// DOFEN inference fused pipeline — fp32 I/O.
// Shapes: B=1024, NCOL=NCOND=64, NRODT=1024, D=4, NEST=128, NFOREST=100,
//         NHID=128, NCLASS=10.
//
// Round 5: k_forest occupancy + overhead fix.
//  - ws kept in registers; F-loop broadcasts via __shfl (no ws4 LDS).
//  - swr read with uniform index in F-loop -> s_load + SGPR-base E addressing.
//  - LDS = zq4 only (8 KB) -> 16 blocks/CU (wave-slot limited, ~100% occ).
//  - zero __syncthreads (zq4 is 32-lane-group-private; DS in-order per wave).
//  - lin1 walks k in memory order, zq index swizzled.
//  - k_rodt: 4 batch rows per thread (params amortized 4x).

#define B_      1024
#define NCOL_   64
#define NCOND_  64
#define NRODT_  1024
#define D_      4
#define NEST_   128
#define NFOREST_ 100
#define NHID_   128
#define NCLASS_ 10
#define EPS_    1e-5f
#define RPT_    4                 // batch rows per thread
#define RPB_    16                // batch rows per block (4 groups x 4)

// ---------------------------------------------------------------------------
// 32-lane group reductions (offsets <=16 never cross the 32-lane boundary).
// ---------------------------------------------------------------------------
__device__ __forceinline__ float grp32_sum(float v)
{
#pragma unroll
    for (int o = 16; o; o >>= 1) v += __shfl_xor(v, o);
    return v;
}
__device__ __forceinline__ float grp32_max(float v)
{
#pragma unroll
    for (int o = 16; o; o >>= 1) v = fmaxf(v, __shfl_xor(v, o));
    return v;
}

// ---------------------------------------------------------------------------
// Kernel 1: per-(b,g) rODT weight; 4 batch rows per thread.
// grid = (B_/4) * (NRODT_/256); g = (blockIdx&3)*256+tid; b0 = (blockIdx>>2)*4.
// ---------------------------------------------------------------------------
__global__ __launch_bounds__(256, 4) void k_rodt(
    const float* __restrict__ x,    const float* __restrict__ w1,
    const float* __restrict__ b1,   const int*  __restrict__ perm,
    const float* __restrict__ gn1g, const float* __restrict__ gn1b,
    const float* __restrict__ w2a,  const float* __restrict__ b2a,
    const float* __restrict__ gn2g, const float* __restrict__ gn2b,
    const float* __restrict__ w2b,  const float* __restrict__ b2b,
    float* __restrict__ wout)
{
    int g  = (blockIdx.x & 3) * 256 + threadIdx.x;
    int b0 = (blockIdx.x >> 2) * 4;

    // ---- per-g parameters, loaded once ----
    int4 p4 = ((const int4*)perm)[g];
    int col[4]  = { p4.x & 63, p4.y & 63, p4.z & 63, p4.w & 63 };
    int cond[4] = { p4.x >> 6, p4.y >> 6, p4.z >> 6, p4.w >> 6 };
    float w1v[4], b1v[4];
#pragma unroll
    for (int j = 0; j < 4; ++j) {
        w1v[j] = w1[col[j] * NCOND_ + cond[j]];
        b1v[j] = b1[col[j] * NCOND_ + cond[j]];
    }
    float4 g1  = ((const float4*)gn1g)[g];
    float4 o1  = ((const float4*)gn1b)[g];
    float4 ba  = ((const float4*)b2a)[g];
    float4 g2  = ((const float4*)gn2g)[g];
    float4 o2  = ((const float4*)gn2b)[g];
    float4 wb4 = ((const float4*)w2b)[g];
    float  bb  = b2b[g];
    float4 wa[4];
    const float4* w2a4 = (const float4*)w2a;
#pragma unroll
    for (int i = 0; i < 4; ++i) wa[i] = w2a4[g * 4 + i];

#pragma unroll
    for (int bi = 0; bi < 4; ++bi) {
        const float* xb = x + (b0 + bi) * NCOL_;
        float v[4];
#pragma unroll
        for (int j = 0; j < 4; ++j) {
            float t = xb[col[j]] * w1v[j] + b1v[j];
            v[j] = 1.0f / (1.0f + expf(-t));
        }
        float mu = (v[0] + v[1] + v[2] + v[3]) * 0.25f;
        float var = 0.f;
#pragma unroll
        for (int j = 0; j < 4; ++j) { float d = v[j] - mu; var += d * d; }
        var *= 0.25f;
        float rs = rsqrtf(var + EPS_);
        float h[4];
        h[0] = (v[0] - mu) * rs * g1.x + o1.x;
        h[1] = (v[1] - mu) * rs * g1.y + o1.y;
        h[2] = (v[2] - mu) * rs * g1.z + o1.z;
        h[3] = (v[3] - mu) * rs * g1.w + o1.w;

        float4 a = ba;
#pragma unroll
        for (int i = 0; i < 4; ++i) {
            a.x += h[i] * wa[i].x; a.y += h[i] * wa[i].y;
            a.z += h[i] * wa[i].z; a.w += h[i] * wa[i].w;
        }
        float t2[4];
        t2[0] = fmaxf(a.x, 0.f); t2[1] = fmaxf(a.y, 0.f);
        t2[2] = fmaxf(a.z, 0.f); t2[3] = fmaxf(a.w, 0.f);

        float mu2 = (t2[0] + t2[1] + t2[2] + t2[3]) * 0.25f;
        float var2 = 0.f;
#pragma unroll
        for (int j = 0; j < 4; ++j) { float d = t2[j] - mu2; var2 += d * d; }
        var2 *= 0.25f;
        float rs2 = rsqrtf(var2 + EPS_);

        float wvv = bb;
        wvv += ((t2[0] - mu2) * rs2 * g2.x + o2.x) * wb4.x;
        wvv += ((t2[1] - mu2) * rs2 * g2.y + o2.y) * wb4.y;
        wvv += ((t2[2] - mu2) * rs2 * g2.z + o2.z) * wb4.z;
        wvv += ((t2[3] - mu2) * rs2 * g2.w + o2.w) * wb4.w;
        wout[(b0 + bi) * NRODT_ + g] = wvv;
    }
}

// ---------------------------------------------------------------------------
// Kernel 2: block = (f, 16 batch rows).  128 threads: rg=tid>>5 (4 rows),
// hq=tid&31 (hidden quad 4hq..4hq+3).  No barriers, 8 KB LDS.
// ---------------------------------------------------------------------------
__global__ __launch_bounds__(128, 8) void k_forest(
    const float* __restrict__ wv,    const int*  __restrict__ swr,
    const float* __restrict__ E,
    const float* __restrict__ ln1g,  const float* __restrict__ ln1b,
    const float* __restrict__ lin1w, const float* __restrict__ lin1b,
    const float* __restrict__ ln2g,  const float* __restrict__ ln2b,
    const float* __restrict__ lin2w, float* __restrict__ acc)
{
    __shared__ __align__(16) float4 zq4[4][NHID_];   // [rg][(c<<5)|hq] -> z[rows][4hq+c]

    int tid = threadIdx.x;
    int rg  = tid >> 5;
    int hq  = tid & 31;
    int base32 = tid & 32;                     // wave-half base for shuffles
    int f   = blockIdx.x >> 6;                 // / (B_/RPB_) = /64
    int bt  = blockIdx.x & 63;
    int b0  = bt * RPB_ + rg * RPT_;

    const int* swrf = swr + f * NEST_;

    // ---- softmax over 128 estimators, 4 rows/thread; ws stays in w0 regs ----
    float w0[RPT_][4];                         // [row][j], estimator e = 32j+hq
#pragma unroll
    for (int j = 0; j < 4; ++j) {
        int r = swrf[32 * j + hq];             // per-lane vector load
#pragma unroll
        for (int row = 0; row < RPT_; ++row)
            w0[row][j] = wv[(b0 + row) * NRODT_ + r];
    }
#pragma unroll
    for (int row = 0; row < RPT_; ++row) {
        float m = fmaxf(fmaxf(w0[row][0], w0[row][1]), fmaxf(w0[row][2], w0[row][3]));
        m = grp32_max(m);
        float s = 0.f;
#pragma unroll
        for (int j = 0; j < 4; ++j) { w0[row][j] = expf(w0[row][j] - m); s += w0[row][j]; }
        s = grp32_sum(s);
        float inv = 1.f / s;
#pragma unroll
        for (int j = 0; j < 4; ++j) w0[row][j] *= inv;
    }

    // ---- F[rows][4hq..4hq+3] = sum_e ws[row][e] * E[r_e, :] ----
    // r uniform -> s_load; ws broadcast via shfl from lane (e&31) of this half.
    const float4* E4 = (const float4*)E;
    float4 Fa[RPT_];
#pragma unroll
    for (int row = 0; row < RPT_; ++row) Fa[row] = make_float4(0.f, 0.f, 0.f, 0.f);
#pragma unroll
    for (int j = 0; j < 4; ++j) {
#pragma unroll 8
        for (int e2 = 0; e2 < 32; ++e2) {
            int r = swrf[j * 32 + e2];         // uniform index -> scalar load
            float4 Ev = E4[r * (NHID_ / 4) + hq];
            int src = base32 | e2;
            float a0 = __shfl(w0[0][j], src);
            float a1 = __shfl(w0[1][j], src);
            float a2 = __shfl(w0[2][j], src);
            float a3 = __shfl(w0[3][j], src);
            Fa[0].x += a0 * Ev.x; Fa[0].y += a0 * Ev.y; Fa[0].z += a0 * Ev.z; Fa[0].w += a0 * Ev.w;
            Fa[1].x += a1 * Ev.x; Fa[1].y += a1 * Ev.y; Fa[1].z += a1 * Ev.z; Fa[1].w += a1 * Ev.w;
            Fa[2].x += a2 * Ev.x; Fa[2].y += a2 * Ev.y; Fa[2].z += a2 * Ev.z; Fa[2].w += a2 * Ev.w;
            Fa[3].x += a3 * Ev.x; Fa[3].y += a3 * Ev.y; Fa[3].z += a3 * Ev.z; Fa[3].w += a3 * Ev.w;
        }
    }

    // ---- LayerNorm 1 per row; z -> zq4 (swizzled quads, group-private) ----
    float4 g1 = ((const float4*)ln1g)[hq];
    float4 o1 = ((const float4*)ln1b)[hq];
    float z[RPT_][4];
#pragma unroll
    for (int row = 0; row < RPT_; ++row) {
        float mu  = grp32_sum(Fa[row].x + Fa[row].y + Fa[row].z + Fa[row].w) * (1.f / NHID_);
        float dx = Fa[row].x - mu, dy = Fa[row].y - mu, dz = Fa[row].z - mu, dw = Fa[row].w - mu;
        float var = grp32_sum(dx * dx + dy * dy + dz * dz + dw * dw) * (1.f / NHID_);
        float rs  = rsqrtf(var + EPS_);
        z[row][0] = dx * rs * g1.x + o1.x;
        z[row][1] = dy * rs * g1.y + o1.y;
        z[row][2] = dz * rs * g1.z + o1.z;
        z[row][3] = dw * rs * g1.w + o1.w;
    }
#pragma unroll
    for (int c = 0; c < 4; ++c)     // quad (c<<5)|hq <- z[rows][4hq+c]
        zq4[rg][(c << 5) | hq] = make_float4(z[0][c], z[1][c], z[2][c], z[3][c]);

    // ---- lin1 (128x128) + ReLU: k in memory order, zq index swizzled ----
    const float4* W14 = (const float4*)lin1w;
    float4 bbv = ((const float4*)lin1b)[hq];
    float4 a[RPT_];
#pragma unroll
    for (int row = 0; row < RPT_; ++row) a[row] = bbv;
#pragma unroll 8
    for (int k = 0; k < NHID_; ++k) {
        int q = ((k & 3) << 5) | (k >> 2);     // z[rows][k] lives at zq4[rg][q]
        float4 zq = zq4[rg][q];                // broadcast read
        float4 Wv = W14[k * (NHID_ / 4) + hq];
        a[0].x += zq.x * Wv.x; a[0].y += zq.x * Wv.y; a[0].z += zq.x * Wv.z; a[0].w += zq.x * Wv.w;
        a[1].x += zq.y * Wv.x; a[1].y += zq.y * Wv.y; a[1].z += zq.y * Wv.z; a[1].w += zq.y * Wv.w;
        a[2].x += zq.z * Wv.x; a[2].y += zq.z * Wv.y; a[2].z += zq.z * Wv.z; a[2].w += zq.z * Wv.w;
        a[3].x += zq.w * Wv.x; a[3].y += zq.w * Wv.y; a[3].z += zq.w * Wv.z; a[3].w += zq.w * Wv.w;
    }

    // ---- ReLU + LayerNorm 2 per row; z2 -> zq4 (overwrite, group-private) ----
    float4 g2 = ((const float4*)ln2g)[hq];
    float4 o2 = ((const float4*)ln2b)[hq];
#pragma unroll
    for (int row = 0; row < RPT_; ++row) {
        float ax = fmaxf(a[row].x, 0.f), ay = fmaxf(a[row].y, 0.f);
        float az = fmaxf(a[row].z, 0.f), aw = fmaxf(a[row].w, 0.f);
        float mu  = grp32_sum(ax + ay + az + aw) * (1.f / NHID_);
        float dx = ax - mu, dy = ay - mu, dz = az - mu, dw = aw - mu;
        float var = grp32_sum(dx * dx + dy * dy + dz * dz + dw * dw) * (1.f / NHID_);
        float rs  = rsqrtf(var + EPS_);
        z[row][0] = dx * rs * g2.x + o2.x;
        z[row][1] = dy * rs * g2.y + o2.y;
        z[row][2] = dz * rs * g2.z + o2.z;
        z[row][3] = dw * rs * g2.w + o2.w;
    }
#pragma unroll
    for (int c = 0; c < 4; ++c)
        zq4[rg][(c << 5) | hq] = make_float4(z[0][c], z[1][c], z[2][c], z[3][c]);

    // ---- lin2 (128x10): lanes 0..29 = (class, k-third); combine; atomics ----
    float p0 = 0.f, p1 = 0.f, p2 = 0.f, p3 = 0.f;
    if (hq < 30) {
        int part = hq / 10;
        int cls  = hq - part * 10;
        int qs = (part == 0) ? 0 : (part == 1 ? 43 : 86);
        int qe = (part == 0) ? 43 : (part == 1 ? 86 : 128);
        for (int q = qs; q < qe; ++q) {
            int k = ((q & 31) << 2) | (q >> 5);
            float4 zq = zq4[rg][q];
            float wl = lin2w[k * NCLASS_ + cls];
            p0 += zq.x * wl; p1 += zq.y * wl; p2 += zq.z * wl; p3 += zq.w * wl;
        }
    }
    p0 += __shfl_down(p0, 10) + __shfl_down(p0, 20);
    p1 += __shfl_down(p1, 10) + __shfl_down(p1, 20);
    p2 += __shfl_down(p2, 10) + __shfl_down(p2, 20);
    p3 += __shfl_down(p3, 10) + __shfl_down(p3, 20);
    if (hq < NCLASS_) {
        atomicAdd(&acc[(b0 + 0) * NCLASS_ + hq], p0);
        atomicAdd(&acc[(b0 + 1) * NCLASS_ + hq], p1);
        atomicAdd(&acc[(b0 + 2) * NCLASS_ + hq], p2);
        atomicAdd(&acc[(b0 + 3) * NCLASS_ + hq], p3);
    }
}

// ---------------------------------------------------------------------------
// Kernel 3: out = acc/NFOREST + lin2_b
// ---------------------------------------------------------------------------
__global__ __launch_bounds__(256) void k_final(
    const float* __restrict__ acc, const float* __restrict__ lin2b,
    float* __restrict__ out)
{
    int i = blockIdx.x * 256 + threadIdx.x;
    if (i < B_ * NCLASS_) {
        int c = i % NCLASS_;
        out[i] = acc[i] * (1.f / NFOREST_) + lin2b[c];
    }
}

// ---------------------------------------------------------------------------
extern "C" void kernel_launch(void* const* d_in, const int* in_sizes, int n_in,
                              void* d_out, int out_size, void* d_ws, size_t ws_size,
                              hipStream_t stream)
{
    const float* x     = (const float*)d_in[0];
    const float* w1    = (const float*)d_in[1];
    const float* b1    = (const float*)d_in[2];
    const int*   perm  = (const int*)  d_in[3];
    const float* gn1g  = (const float*)d_in[4];
    const float* gn1b  = (const float*)d_in[5];
    const float* w2a   = (const float*)d_in[6];
    const float* b2a   = (const float*)d_in[7];
    const float* gn2g  = (const float*)d_in[8];
    const float* gn2b  = (const float*)d_in[9];
    const float* w2b   = (const float*)d_in[10];
    const float* b2b   = (const float*)d_in[11];
    const float* E     = (const float*)d_in[12];
    const int*   swr   = (const int*)  d_in[13];
    const float* ln1g  = (const float*)d_in[14];
    const float* ln1b  = (const float*)d_in[15];
    const float* lin1w = (const float*)d_in[16];
    const float* lin1b = (const float*)d_in[17];
    const float* ln2g  = (const float*)d_in[18];
    const float* ln2b  = (const float*)d_in[19];
    const float* lin2w = (const float*)d_in[20];
    const float* lin2b = (const float*)d_in[21];

    float* w_ws = (float*)d_ws;                                   // B*NRODT fp32
    float* accp = (float*)((char*)d_ws + (size_t)B_ * NRODT_ * sizeof(float));

    hipMemsetAsync(accp, 0, (size_t)B_ * NCLASS_ * sizeof(float), stream);

    k_rodt<<<(B_ / 4) * (NRODT_ / 256), 256, 0, stream>>>(
        x, w1, b1, perm, gn1g, gn1b, w2a, b2a, gn2g, gn2b, w2b, b2b, w_ws);

    k_forest<<<NFOREST_ * (B_ / RPB_), 128, 0, stream>>>(
        w_ws, swr, E, ln1g, ln1b, lin1w, lin1b, ln2g, ln2b, lin2w, accp);

    k_final<<<(B_ * NCLASS_ + 255) / 256, 256, 0, stream>>>(
        accp, lin2b, (float*)d_out);
}

// Round 6
// 162.251 us; speedup vs baseline: 3.9194x; 1.6550x over previous
//
#include <hip/hip_runtime.h>

// DOFEN inference fused pipeline — fp32 I/O, MFMA core.
// Shapes: B=1024, NCOL=NCOND=64, NRODT=1024, D=4, NEST=128, NFOREST=100,
//         NHID=128, NCLASS=10.
//
// Round 6: k_forest rebuilt on mfma_f32_16x16x32_bf16.
//  - block = (forest, 16 batch rows), 256 thr = 4 waves; wave w owns cols [32w,32w+32).
//  - A (ws, z) single bf16 (error fresh per (b,f), averages over forests);
//    B (E, lin1w, lin2w) split hi+lo bf16 (correlated error) -> 2 MFMA/k-step.
//  - k_prep pre-swizzles B into fragment-contiguous layout:
//    frag[t= (mat,kk,nn)*64+lane][j] = B[kk*32+(lane>>4)*8+j][nn*16+(lane&15)]
//    so each B-load is one coalesced dwordx4.  Esel gathered per forest.
//  - softmax computed in A-frag lanes (m=lane&15, k=q*8+j+32kk) from w_t[g][b];
//    k_rodt rewritten: one g per block (params scalar-uniform), coalesced w_t write.
//  - C-layout (col=lane&15,row=q*4+reg) -> A-layout via XOR-swizzled LDS
//    (phys_dw = dw ^ ((row&7)<<2)): conflict-free writes and min-cycle reads.

#define B_      1024
#define NCOL_   64
#define NCOND_  64
#define NRODT_  1024
#define NEST_   128
#define NFOREST_ 100
#define NHID_   128
#define NCLASS_ 10
#define EPS_    1e-5f

typedef __bf16 bf16_t;
typedef bf16_t bf16x8 __attribute__((ext_vector_type(8)));
typedef float  f32x4  __attribute__((ext_vector_type(4)));

#define MFMA16(a,b,c) __builtin_amdgcn_mfma_f32_16x16x32_bf16(a,b,c,0,0,0)

#define EG_FRAGS   (NFOREST_*4*8*64)   // 204800 frag-rows of 8 bf16
#define W1_FRAGS   (4*8*64)            // 2048
#define L2_FRAGS   (4*64)              // 256

// ---------------------------------------------------------------------------
// k_prep: build B-fragment tables (Esel per forest, lin1w, lin2w hi/lo) + x_t.
// grid = 1065 blocks x 256.
// ---------------------------------------------------------------------------
__global__ __launch_bounds__(256) void k_prep(
    const float* __restrict__ E,     const int*   __restrict__ swr,
    const float* __restrict__ lin1w, const float* __restrict__ lin2w,
    const float* __restrict__ x,
    bf16_t* __restrict__ Eh,  bf16_t* __restrict__ El,
    bf16_t* __restrict__ Wh,  bf16_t* __restrict__ Wl,
    bf16_t* __restrict__ L2h, bf16_t* __restrict__ L2l,
    float*  __restrict__ x_t)
{
    int blk = blockIdx.x, tid = threadIdx.x;
    if (blk < 800) {                              // Esel frags: t=(((f*4+kk)*8+nn)*64+lane)
        int t = blk * 256 + tid;
        int lane = t & 63, nn = (t >> 6) & 7, kk = (t >> 9) & 3, f = t >> 11;
        int q = lane >> 4, n = nn * 16 + (lane & 15);
        bf16x8 hi, lo;
#pragma unroll
        for (int j = 0; j < 8; ++j) {
            int e = kk * 32 + q * 8 + j;
            int r = swr[f * NEST_ + e];
            float v = E[r * NHID_ + n];
            bf16_t h = (bf16_t)v;
            hi[j] = h; lo[j] = (bf16_t)(v - (float)h);
        }
        *(bf16x8*)(Eh + (size_t)t * 8) = hi;
        *(bf16x8*)(El + (size_t)t * 8) = lo;
    } else if (blk < 808) {                       // lin1w frags: t=(kk*8+nn)*64+lane
        int t = (blk - 800) * 256 + tid;
        int lane = t & 63, nn = (t >> 6) & 7, kk = t >> 9;
        int q = lane >> 4, n = nn * 16 + (lane & 15);
        bf16x8 hi, lo;
#pragma unroll
        for (int j = 0; j < 8; ++j) {
            int k = kk * 32 + q * 8 + j;
            float v = lin1w[k * NHID_ + n];
            bf16_t h = (bf16_t)v;
            hi[j] = h; lo[j] = (bf16_t)(v - (float)h);
        }
        *(bf16x8*)(Wh + t * 8) = hi;
        *(bf16x8*)(Wl + t * 8) = lo;
    } else if (blk == 808) {                      // lin2w frags (N padded to 16): t=kk*64+lane
        int t = tid;
        int lane = t & 63, kk = t >> 6;
        int q = lane >> 4, n = lane & 15;
        bf16x8 hi, lo;
#pragma unroll
        for (int j = 0; j < 8; ++j) {
            int k = kk * 32 + q * 8 + j;
            float v = (n < NCLASS_) ? lin2w[k * NCLASS_ + n] : 0.f;
            bf16_t h = (bf16_t)v;
            hi[j] = h; lo[j] = (bf16_t)(v - (float)h);
        }
        *(bf16x8*)(L2h + t * 8) = hi;
        *(bf16x8*)(L2l + t * 8) = lo;
    } else {                                      // x_t[col][b] = x[b][col]
        int t = (blk - 809) * 256 + tid;          // col = t>>10, b = t&1023
        x_t[t] = x[(t & 1023) * NCOL_ + (t >> 10)];
    }
}

// ---------------------------------------------------------------------------
// k_rodt: one g per block (params scalar-uniform); thread handles 4 b's via
// float4 x_t loads; coalesced float4 write of w_t[g][b].
// ---------------------------------------------------------------------------
__global__ __launch_bounds__(256) void k_rodt(
    const float* __restrict__ x_t,  const float* __restrict__ w1,
    const float* __restrict__ b1,   const int*  __restrict__ perm,
    const float* __restrict__ gn1g, const float* __restrict__ gn1b,
    const float* __restrict__ w2a,  const float* __restrict__ b2a,
    const float* __restrict__ gn2g, const float* __restrict__ gn2b,
    const float* __restrict__ w2b,  const float* __restrict__ b2b,
    float* __restrict__ w_t)
{
    int g  = blockIdx.x;
    int bq = threadIdx.x * 4;

    int4 p4 = ((const int4*)perm)[g];
    int col[4]  = { p4.x & 63, p4.y & 63, p4.z & 63, p4.w & 63 };
    int cond[4] = { p4.x >> 6, p4.y >> 6, p4.z >> 6, p4.w >> 6 };
    float w1v[4], b1v[4];
#pragma unroll
    for (int j = 0; j < 4; ++j) {
        w1v[j] = w1[col[j] * NCOND_ + cond[j]];
        b1v[j] = b1[col[j] * NCOND_ + cond[j]];
    }
    float4 g1  = ((const float4*)gn1g)[g];
    float4 o1  = ((const float4*)gn1b)[g];
    float4 ba  = ((const float4*)b2a)[g];
    float4 g2  = ((const float4*)gn2g)[g];
    float4 o2  = ((const float4*)gn2b)[g];
    float4 wb4 = ((const float4*)w2b)[g];
    float  bb  = b2b[g];
    float4 wa[4];
    const float4* w2a4 = (const float4*)w2a;
#pragma unroll
    for (int i = 0; i < 4; ++i) wa[i] = w2a4[g * 4 + i];

    float xv[4][4];
#pragma unroll
    for (int j = 0; j < 4; ++j) {
        float4 t = *(const float4*)&x_t[col[j] * B_ + bq];
        xv[j][0] = t.x; xv[j][1] = t.y; xv[j][2] = t.z; xv[j][3] = t.w;
    }

    float outv[4];
#pragma unroll
    for (int bi = 0; bi < 4; ++bi) {
        float v[4];
#pragma unroll
        for (int j = 0; j < 4; ++j) {
            float t = xv[j][bi] * w1v[j] + b1v[j];
            v[j] = 1.0f / (1.0f + expf(-t));
        }
        float mu = (v[0] + v[1] + v[2] + v[3]) * 0.25f;
        float var = 0.f;
#pragma unroll
        for (int j = 0; j < 4; ++j) { float d = v[j] - mu; var += d * d; }
        var *= 0.25f;
        float rs = rsqrtf(var + EPS_);
        float h[4];
        h[0] = (v[0] - mu) * rs * g1.x + o1.x;
        h[1] = (v[1] - mu) * rs * g1.y + o1.y;
        h[2] = (v[2] - mu) * rs * g1.z + o1.z;
        h[3] = (v[3] - mu) * rs * g1.w + o1.w;

        float4 a = ba;
#pragma unroll
        for (int i = 0; i < 4; ++i) {
            a.x += h[i] * wa[i].x; a.y += h[i] * wa[i].y;
            a.z += h[i] * wa[i].z; a.w += h[i] * wa[i].w;
        }
        float t2[4];
        t2[0] = fmaxf(a.x, 0.f); t2[1] = fmaxf(a.y, 0.f);
        t2[2] = fmaxf(a.z, 0.f); t2[3] = fmaxf(a.w, 0.f);

        float mu2 = (t2[0] + t2[1] + t2[2] + t2[3]) * 0.25f;
        float var2 = 0.f;
#pragma unroll
        for (int j = 0; j < 4; ++j) { float d = t2[j] - mu2; var2 += d * d; }
        var2 *= 0.25f;
        float rs2 = rsqrtf(var2 + EPS_);

        float wvv = bb;
        wvv += ((t2[0] - mu2) * rs2 * g2.x + o2.x) * wb4.x;
        wvv += ((t2[1] - mu2) * rs2 * g2.y + o2.y) * wb4.y;
        wvv += ((t2[2] - mu2) * rs2 * g2.z + o2.z) * wb4.z;
        wvv += ((t2[3] - mu2) * rs2 * g2.w + o2.w) * wb4.w;
        outv[bi] = wvv;
    }
    *(float4*)&w_t[(size_t)g * B_ + bq] = make_float4(outv[0], outv[1], outv[2], outv[3]);
}

// ---------------------------------------------------------------------------
// k_forest: MFMA pipeline.  256 thr = 4 waves; wave w -> n-tiles {2w, 2w+1}.
// lane: q=lane>>4, mc=lane&15.  A row m=mc, k=q*8+j (+32kk).  C: row=q*4+reg,
// col=tile*16+mc.
// ---------------------------------------------------------------------------
__global__ __launch_bounds__(256, 4) void k_forest(
    const float*  __restrict__ w_t, const int* __restrict__ swr,
    const bf16_t* __restrict__ Eh,  const bf16_t* __restrict__ El,
    const bf16_t* __restrict__ Wh,  const bf16_t* __restrict__ Wl,
    const bf16_t* __restrict__ L2h, const bf16_t* __restrict__ L2l,
    const float* __restrict__ ln1g, const float* __restrict__ ln1b,
    const float* __restrict__ lin1b,
    const float* __restrict__ ln2g, const float* __restrict__ ln2b,
    float* __restrict__ acc)
{
    __shared__ float  zsh[16 * 128];      // XOR-swizzled 16x128 tile
    __shared__ float2 stats[4][16];       // [wave][row] {sum, sumsq}

    int tid  = threadIdx.x;
    int w    = tid >> 6;
    int lane = tid & 63;
    int q    = lane >> 4;
    int mc   = lane & 15;
    int f    = blockIdx.x >> 6;
    int b0   = (blockIdx.x & 63) * 16;

    const int* swrf = swr + f * NEST_;

    // ---- softmax in A-frag lanes: ws[m=mc][e=kk*32+q*8+j] ----
    float ex[4][8];
    float mx = -1e30f;
#pragma unroll
    for (int kk = 0; kk < 4; ++kk) {
        int4 r0 = *(const int4*)(swrf + kk * 32 + q * 8);
        int4 r1 = *(const int4*)(swrf + kk * 32 + q * 8 + 4);
        int rr[8] = { r0.x, r0.y, r0.z, r0.w, r1.x, r1.y, r1.z, r1.w };
#pragma unroll
        for (int j = 0; j < 8; ++j) {
            float v = w_t[rr[j] * B_ + b0 + mc];
            ex[kk][j] = v;
            mx = fmaxf(mx, v);
        }
    }
    mx = fmaxf(mx, __shfl_xor(mx, 16));
    mx = fmaxf(mx, __shfl_xor(mx, 32));
    float s = 0.f;
#pragma unroll
    for (int kk = 0; kk < 4; ++kk)
#pragma unroll
        for (int j = 0; j < 8; ++j) { ex[kk][j] = __expf(ex[kk][j] - mx); s += ex[kk][j]; }
    s += __shfl_xor(s, 16);
    s += __shfl_xor(s, 32);
    float inv = 1.f / s;

    bf16x8 afr[4];
#pragma unroll
    for (int kk = 0; kk < 4; ++kk)
#pragma unroll
        for (int j = 0; j < 8; ++j) afr[kk][j] = (bf16_t)(ex[kk][j] * inv);

    // ---- F-GEMM: 2 n-tiles, K=128, B split hi/lo ----
    int nn0 = w * 2, nn1 = nn0 + 1;
    f32x4 accF0 = {0.f, 0.f, 0.f, 0.f}, accF1 = {0.f, 0.f, 0.f, 0.f};
    const bf16x8* EHf = (const bf16x8*)Eh;
    const bf16x8* ELf = (const bf16x8*)El;
#pragma unroll
    for (int kk = 0; kk < 4; ++kk) {
        size_t bi = (size_t)(f * 4 + kk) * 8;
        bf16x8 bh0 = EHf[(bi + nn0) * 64 + lane];
        bf16x8 bl0 = ELf[(bi + nn0) * 64 + lane];
        bf16x8 bh1 = EHf[(bi + nn1) * 64 + lane];
        bf16x8 bl1 = ELf[(bi + nn1) * 64 + lane];
        accF0 = MFMA16(afr[kk], bh0, accF0);
        accF0 = MFMA16(afr[kk], bl0, accF0);
        accF1 = MFMA16(afr[kk], bh1, accF1);
        accF1 = MFMA16(afr[kk], bl1, accF1);
    }

    // ---- LayerNorm 1 (rows q*4+reg): shfl partials + LDS combine ----
#pragma unroll
    for (int reg = 0; reg < 4; ++reg) {
        float ps = accF0[reg] + accF1[reg];
        float pq = accF0[reg] * accF0[reg] + accF1[reg] * accF1[reg];
#pragma unroll
        for (int o = 1; o <= 8; o <<= 1) { ps += __shfl_xor(ps, o); pq += __shfl_xor(pq, o); }
        if (mc == 0) stats[w][q * 4 + reg] = make_float2(ps, pq);
    }
    __syncthreads();                                   // barrier 1
    float mu[4], rs[4];
#pragma unroll
    for (int reg = 0; reg < 4; ++reg) {
        int r = q * 4 + reg;
        float2 s0 = stats[0][r], s1 = stats[1][r], s2 = stats[2][r], s3 = stats[3][r];
        float sm = s0.x + s1.x + s2.x + s3.x;
        float sq = s0.y + s1.y + s2.y + s3.y;
        float m_ = sm * (1.f / NHID_);
        mu[reg] = m_;
        rs[reg] = rsqrtf(sq * (1.f / NHID_) - m_ * m_ + EPS_);
    }
    int c0 = w * 32 + mc, c1 = c0 + 16;
    {
        float g1a = ln1g[c0], g1b = ln1g[c1], o1a = ln1b[c0], o1b = ln1b[c1];
#pragma unroll
        for (int reg = 0; reg < 4; ++reg) {
            int row = q * 4 + reg, xr = (row & 7) << 2;
            zsh[row * 128 + (c0 ^ xr)] = (accF0[reg] - mu[reg]) * rs[reg] * g1a + o1a;
            zsh[row * 128 + (c1 ^ xr)] = (accF1[reg] - mu[reg]) * rs[reg] * g1b + o1b;
        }
    }
    __syncthreads();                                   // barrier 2

    // ---- lin1 GEMM: A from zsh (single bf16), B = Wh/Wl ----
    bf16x8 a2[4];
    int xrm = (mc & 7) << 2;
#pragma unroll
    for (int kk = 0; kk < 4; ++kk) {
        int dwb = kk * 32 + q * 8;
        f32x4 u0 = *(const f32x4*)&zsh[mc * 128 + ((dwb    ) ^ xrm)];
        f32x4 u1 = *(const f32x4*)&zsh[mc * 128 + ((dwb + 4) ^ xrm)];
#pragma unroll
        for (int j = 0; j < 4; ++j) { a2[kk][j] = (bf16_t)u0[j]; a2[kk][4 + j] = (bf16_t)u1[j]; }
    }
    f32x4 accA0 = {0.f, 0.f, 0.f, 0.f}, accA1 = {0.f, 0.f, 0.f, 0.f};
    const bf16x8* WHf = (const bf16x8*)Wh;
    const bf16x8* WLf = (const bf16x8*)Wl;
#pragma unroll
    for (int kk = 0; kk < 4; ++kk) {
        bf16x8 bh0 = WHf[(kk * 8 + nn0) * 64 + lane];
        bf16x8 bl0 = WLf[(kk * 8 + nn0) * 64 + lane];
        bf16x8 bh1 = WHf[(kk * 8 + nn1) * 64 + lane];
        bf16x8 bl1 = WLf[(kk * 8 + nn1) * 64 + lane];
        accA0 = MFMA16(a2[kk], bh0, accA0);
        accA0 = MFMA16(a2[kk], bl0, accA0);
        accA1 = MFMA16(a2[kk], bh1, accA1);
        accA1 = MFMA16(a2[kk], bl1, accA1);
    }

    // ---- bias + ReLU + LayerNorm 2 ----
    float bb0 = lin1b[c0], bb1 = lin1b[c1];
#pragma unroll
    for (int reg = 0; reg < 4; ++reg) {
        float a0 = fmaxf(accA0[reg] + bb0, 0.f);
        float a1 = fmaxf(accA1[reg] + bb1, 0.f);
        accA0[reg] = a0; accA1[reg] = a1;
        float ps = a0 + a1, pq = a0 * a0 + a1 * a1;
#pragma unroll
        for (int o = 1; o <= 8; o <<= 1) { ps += __shfl_xor(ps, o); pq += __shfl_xor(pq, o); }
        if (mc == 0) stats[w][q * 4 + reg] = make_float2(ps, pq);
    }
    __syncthreads();                                   // barrier 3
    float mu2[4], rs2[4];
#pragma unroll
    for (int reg = 0; reg < 4; ++reg) {
        int r = q * 4 + reg;
        float2 s0 = stats[0][r], s1 = stats[1][r], s2 = stats[2][r], s3 = stats[3][r];
        float sm = s0.x + s1.x + s2.x + s3.x;
        float sq = s0.y + s1.y + s2.y + s3.y;
        float m_ = sm * (1.f / NHID_);
        mu2[reg] = m_;
        rs2[reg] = rsqrtf(sq * (1.f / NHID_) - m_ * m_ + EPS_);
    }
    {
        float g2a = ln2g[c0], g2b = ln2g[c1], o2a = ln2b[c0], o2b = ln2b[c1];
#pragma unroll
        for (int reg = 0; reg < 4; ++reg) {
            int row = q * 4 + reg, xr = (row & 7) << 2;
            zsh[row * 128 + (c0 ^ xr)] = (accA0[reg] - mu2[reg]) * rs2[reg] * g2a + o2a;
            zsh[row * 128 + (c1 ^ xr)] = (accA1[reg] - mu2[reg]) * rs2[reg] * g2b + o2b;
        }
    }
    __syncthreads();                                   // barrier 4

    // ---- lin2 (wave 0 only): 16x128 @ 128x16(padded), accumulate ----
    if (w == 0) {
        f32x4 accO = {0.f, 0.f, 0.f, 0.f};
        const bf16x8* LHf = (const bf16x8*)L2h;
        const bf16x8* LLf = (const bf16x8*)L2l;
#pragma unroll
        for (int kk = 0; kk < 4; ++kk) {
            int dwb = kk * 32 + q * 8;
            f32x4 u0 = *(const f32x4*)&zsh[mc * 128 + ((dwb    ) ^ xrm)];
            f32x4 u1 = *(const f32x4*)&zsh[mc * 128 + ((dwb + 4) ^ xrm)];
            bf16x8 a3;
#pragma unroll
            for (int j = 0; j < 4; ++j) { a3[j] = (bf16_t)u0[j]; a3[4 + j] = (bf16_t)u1[j]; }
            accO = MFMA16(a3, LHf[kk * 64 + lane], accO);
            accO = MFMA16(a3, LLf[kk * 64 + lane], accO);
        }
        if (mc < NCLASS_) {
#pragma unroll
            for (int reg = 0; reg < 4; ++reg)
                atomicAdd(&acc[(b0 + q * 4 + reg) * NCLASS_ + mc], accO[reg]);
        }
    }
}

// ---------------------------------------------------------------------------
// k_final: out = acc/NFOREST + lin2_b
// ---------------------------------------------------------------------------
__global__ __launch_bounds__(256) void k_final(
    const float* __restrict__ acc, const float* __restrict__ lin2b,
    float* __restrict__ out)
{
    int i = blockIdx.x * 256 + threadIdx.x;
    if (i < B_ * NCLASS_) {
        int c = i % NCLASS_;
        out[i] = acc[i] * (1.f / NFOREST_) + lin2b[c];
    }
}

// ---------------------------------------------------------------------------
extern "C" void kernel_launch(void* const* d_in, const int* in_sizes, int n_in,
                              void* d_out, int out_size, void* d_ws, size_t ws_size,
                              hipStream_t stream)
{
    const float* x     = (const float*)d_in[0];
    const float* w1    = (const float*)d_in[1];
    const float* b1    = (const float*)d_in[2];
    const int*   perm  = (const int*)  d_in[3];
    const float* gn1g  = (const float*)d_in[4];
    const float* gn1b  = (const float*)d_in[5];
    const float* w2a   = (const float*)d_in[6];
    const float* b2a   = (const float*)d_in[7];
    const float* gn2g  = (const float*)d_in[8];
    const float* gn2b  = (const float*)d_in[9];
    const float* w2b   = (const float*)d_in[10];
    const float* b2b   = (const float*)d_in[11];
    const float* E     = (const float*)d_in[12];
    const int*   swr   = (const int*)  d_in[13];
    const float* ln1g  = (const float*)d_in[14];
    const float* ln1b  = (const float*)d_in[15];
    const float* lin1w = (const float*)d_in[16];
    const float* lin1b = (const float*)d_in[17];
    const float* ln2g  = (const float*)d_in[18];
    const float* ln2b  = (const float*)d_in[19];
    const float* lin2w = (const float*)d_in[20];
    const float* lin2b = (const float*)d_in[21];

    char* base = (char*)d_ws;
    float*  w_t  = (float*)base;                                    // 4 MB
    float*  accp = (float*)(base + 4u * 1024 * 1024);               // 40 KB
    float*  x_t  = (float*)(base + 4u * 1024 * 1024 + 64 * 1024);   // 256 KB
    bf16_t* Eh   = (bf16_t*)(base + 4u * 1024 * 1024 + 64 * 1024 + 256 * 1024);
    bf16_t* El   = Eh  + (size_t)EG_FRAGS * 8;
    bf16_t* Wh   = El  + (size_t)EG_FRAGS * 8;
    bf16_t* Wl   = Wh  + (size_t)W1_FRAGS * 8;
    bf16_t* L2h  = Wl  + (size_t)W1_FRAGS * 8;
    bf16_t* L2l  = L2h + (size_t)L2_FRAGS * 8;

    hipMemsetAsync(accp, 0, (size_t)B_ * NCLASS_ * sizeof(float), stream);

    k_prep<<<1065, 256, 0, stream>>>(E, swr, lin1w, lin2w, x,
                                     Eh, El, Wh, Wl, L2h, L2l, x_t);

    k_rodt<<<NRODT_, 256, 0, stream>>>(
        x_t, w1, b1, perm, gn1g, gn1b, w2a, b2a, gn2g, gn2b, w2b, b2b, w_t);

    k_forest<<<NFOREST_ * 64, 256, 0, stream>>>(
        w_t, swr, Eh, El, Wh, Wl, L2h, L2l,
        ln1g, ln1b, lin1b, ln2g, ln2b, accp);

    k_final<<<(B_ * NCLASS_ + 255) / 256, 256, 0, stream>>>(
        accp, lin2b, (float*)d_out);
}

// Round 7
// 150.291 us; speedup vs baseline: 4.2313x; 1.0796x over previous
//
#include <hip/hip_runtime.h>

// DOFEN inference fused pipeline — fp32 I/O, MFMA core.
// Shapes: B=1024, NCOL=NCOND=64, NRODT=1024, D=4, NEST=128, NFOREST=100,
//         NHID=128, NCLASS=10.
//
// Round 7: k_forest block = (forest, 64 batch rows); wave = one 16-row m-tile
// owning all 8 n-tiles.  All reductions wave-internal -> ZERO barriers.
// LDS: per-wave 16x132 fp32 z-tile (pad 132: scatter-write 2-way-free,
// b128 read uniform).  XCD swizzle co-locates each forest's blocks.
// k_prep also zeroes acc (memset node removed).  A=bf16, B=hi+lo bf16.

#define B_      1024
#define NCOL_   64
#define NCOND_  64
#define NRODT_  1024
#define NEST_   128
#define NFOREST_ 100
#define NHID_   128
#define NCLASS_ 10
#define EPS_    1e-5f

typedef __bf16 bf16_t;
typedef bf16_t bf16x8 __attribute__((ext_vector_type(8)));
typedef float  f32x4  __attribute__((ext_vector_type(4)));

#define MFMA16(a,b,c) __builtin_amdgcn_mfma_f32_16x16x32_bf16(a,b,c,0,0,0)

#define EG_FRAGS   (NFOREST_*4*8*64)   // 204800 frag-rows of 8 bf16
#define W1_FRAGS   (4*8*64)            // 2048
#define L2_FRAGS   (4*64)              // 256

// ---------------------------------------------------------------------------
// k_prep: B-fragment tables (Esel/f, lin1w, lin2w hi/lo) + x_t + acc zero.
// grid = 1105 x 256.
// ---------------------------------------------------------------------------
__global__ __launch_bounds__(256) void k_prep(
    const float* __restrict__ E,     const int*   __restrict__ swr,
    const float* __restrict__ lin1w, const float* __restrict__ lin2w,
    const float* __restrict__ x,
    bf16_t* __restrict__ Eh,  bf16_t* __restrict__ El,
    bf16_t* __restrict__ Wh,  bf16_t* __restrict__ Wl,
    bf16_t* __restrict__ L2h, bf16_t* __restrict__ L2l,
    float*  __restrict__ x_t, float* __restrict__ accz)
{
    int blk = blockIdx.x, tid = threadIdx.x;
    if (blk < 800) {                              // Esel frags: t=(((f*4+kk)*8+nn)*64+lane)
        int t = blk * 256 + tid;
        int lane = t & 63, nn = (t >> 6) & 7, kk = (t >> 9) & 3, f = t >> 11;
        int q = lane >> 4, n = nn * 16 + (lane & 15);
        bf16x8 hi, lo;
#pragma unroll
        for (int j = 0; j < 8; ++j) {
            int e = kk * 32 + q * 8 + j;
            int r = swr[f * NEST_ + e];
            float v = E[r * NHID_ + n];
            bf16_t h = (bf16_t)v;
            hi[j] = h; lo[j] = (bf16_t)(v - (float)h);
        }
        *(bf16x8*)(Eh + (size_t)t * 8) = hi;
        *(bf16x8*)(El + (size_t)t * 8) = lo;
    } else if (blk < 808) {                       // lin1w frags: t=(kk*8+nn)*64+lane
        int t = (blk - 800) * 256 + tid;
        int lane = t & 63, nn = (t >> 6) & 7, kk = t >> 9;
        int q = lane >> 4, n = nn * 16 + (lane & 15);
        bf16x8 hi, lo;
#pragma unroll
        for (int j = 0; j < 8; ++j) {
            int k = kk * 32 + q * 8 + j;
            float v = lin1w[k * NHID_ + n];
            bf16_t h = (bf16_t)v;
            hi[j] = h; lo[j] = (bf16_t)(v - (float)h);
        }
        *(bf16x8*)(Wh + t * 8) = hi;
        *(bf16x8*)(Wl + t * 8) = lo;
    } else if (blk == 808) {                      // lin2w frags (N pad 16): t=kk*64+lane
        int t = tid;
        int lane = t & 63, kk = t >> 6;
        int q = lane >> 4, n = lane & 15;
        bf16x8 hi, lo;
#pragma unroll
        for (int j = 0; j < 8; ++j) {
            int k = kk * 32 + q * 8 + j;
            float v = (n < NCLASS_) ? lin2w[k * NCLASS_ + n] : 0.f;
            bf16_t h = (bf16_t)v;
            hi[j] = h; lo[j] = (bf16_t)(v - (float)h);
        }
        *(bf16x8*)(L2h + t * 8) = hi;
        *(bf16x8*)(L2l + t * 8) = lo;
    } else if (blk < 1065) {                      // x_t[col][b] = x[b][col]
        int t = (blk - 809) * 256 + tid;
        x_t[t] = x[(t & 1023) * NCOL_ + (t >> 10)];
    } else {                                      // zero acc (B*NCLASS = 10240)
        int t = (blk - 1065) * 256 + tid;
        if (t < B_ * NCLASS_) accz[t] = 0.f;
    }
}

// ---------------------------------------------------------------------------
// k_rodt: one g per block (params scalar-uniform); thread handles 4 b's.
// ---------------------------------------------------------------------------
__global__ __launch_bounds__(256) void k_rodt(
    const float* __restrict__ x_t,  const float* __restrict__ w1,
    const float* __restrict__ b1,   const int*  __restrict__ perm,
    const float* __restrict__ gn1g, const float* __restrict__ gn1b,
    const float* __restrict__ w2a,  const float* __restrict__ b2a,
    const float* __restrict__ gn2g, const float* __restrict__ gn2b,
    const float* __restrict__ w2b,  const float* __restrict__ b2b,
    float* __restrict__ w_t)
{
    int g  = blockIdx.x;
    int bq = threadIdx.x * 4;

    int4 p4 = ((const int4*)perm)[g];
    int col[4]  = { p4.x & 63, p4.y & 63, p4.z & 63, p4.w & 63 };
    int cond[4] = { p4.x >> 6, p4.y >> 6, p4.z >> 6, p4.w >> 6 };
    float w1v[4], b1v[4];
#pragma unroll
    for (int j = 0; j < 4; ++j) {
        w1v[j] = w1[col[j] * NCOND_ + cond[j]];
        b1v[j] = b1[col[j] * NCOND_ + cond[j]];
    }
    float4 g1  = ((const float4*)gn1g)[g];
    float4 o1  = ((const float4*)gn1b)[g];
    float4 ba  = ((const float4*)b2a)[g];
    float4 g2  = ((const float4*)gn2g)[g];
    float4 o2  = ((const float4*)gn2b)[g];
    float4 wb4 = ((const float4*)w2b)[g];
    float  bb  = b2b[g];
    float4 wa[4];
    const float4* w2a4 = (const float4*)w2a;
#pragma unroll
    for (int i = 0; i < 4; ++i) wa[i] = w2a4[g * 4 + i];

    float xv[4][4];
#pragma unroll
    for (int j = 0; j < 4; ++j) {
        float4 t = *(const float4*)&x_t[col[j] * B_ + bq];
        xv[j][0] = t.x; xv[j][1] = t.y; xv[j][2] = t.z; xv[j][3] = t.w;
    }

    float outv[4];
#pragma unroll
    for (int bi = 0; bi < 4; ++bi) {
        float v[4];
#pragma unroll
        for (int j = 0; j < 4; ++j) {
            float t = xv[j][bi] * w1v[j] + b1v[j];
            v[j] = 1.0f / (1.0f + __expf(-t));
        }
        float mu = (v[0] + v[1] + v[2] + v[3]) * 0.25f;
        float var = 0.f;
#pragma unroll
        for (int j = 0; j < 4; ++j) { float d = v[j] - mu; var += d * d; }
        var *= 0.25f;
        float rs = rsqrtf(var + EPS_);
        float h[4];
        h[0] = (v[0] - mu) * rs * g1.x + o1.x;
        h[1] = (v[1] - mu) * rs * g1.y + o1.y;
        h[2] = (v[2] - mu) * rs * g1.z + o1.z;
        h[3] = (v[3] - mu) * rs * g1.w + o1.w;

        float4 a = ba;
#pragma unroll
        for (int i = 0; i < 4; ++i) {
            a.x += h[i] * wa[i].x; a.y += h[i] * wa[i].y;
            a.z += h[i] * wa[i].z; a.w += h[i] * wa[i].w;
        }
        float t2[4];
        t2[0] = fmaxf(a.x, 0.f); t2[1] = fmaxf(a.y, 0.f);
        t2[2] = fmaxf(a.z, 0.f); t2[3] = fmaxf(a.w, 0.f);

        float mu2 = (t2[0] + t2[1] + t2[2] + t2[3]) * 0.25f;
        float var2 = 0.f;
#pragma unroll
        for (int j = 0; j < 4; ++j) { float d = t2[j] - mu2; var2 += d * d; }
        var2 *= 0.25f;
        float rs2 = rsqrtf(var2 + EPS_);

        float wvv = bb;
        wvv += ((t2[0] - mu2) * rs2 * g2.x + o2.x) * wb4.x;
        wvv += ((t2[1] - mu2) * rs2 * g2.y + o2.y) * wb4.y;
        wvv += ((t2[2] - mu2) * rs2 * g2.z + o2.z) * wb4.z;
        wvv += ((t2[3] - mu2) * rs2 * g2.w + o2.w) * wb4.w;
        outv[bi] = wvv;
    }
    *(float4*)&w_t[(size_t)g * B_ + bq] = make_float4(outv[0], outv[1], outv[2], outv[3]);
}

// ---------------------------------------------------------------------------
// k_forest: block=(f, 64 rows), 4 waves, wave = m-tile (16 rows) x all 8
// n-tiles.  Barrier-free; per-wave 16x132 LDS z-tile.
// lane: q=lane>>4, mc=lane&15.  A: m=mc, k=q*8+j(+32kk).  C: row=q*4+reg,
// col=nn*16+mc.
// ---------------------------------------------------------------------------
__global__ __launch_bounds__(256, 4) void k_forest(
    const float*  __restrict__ w_t, const int* __restrict__ swr,
    const bf16_t* __restrict__ Eh,  const bf16_t* __restrict__ El,
    const bf16_t* __restrict__ Wh,  const bf16_t* __restrict__ Wl,
    const bf16_t* __restrict__ L2h, const bf16_t* __restrict__ L2l,
    const float* __restrict__ ln1g, const float* __restrict__ ln1b,
    const float* __restrict__ lin1b,
    const float* __restrict__ ln2g, const float* __restrict__ ln2b,
    float* __restrict__ acc)
{
    __shared__ float zsh[4][16 * 132];    // per-wave z tile, pad 132

    int tid  = threadIdx.x;
    int wid  = tid >> 6;
    int lane = tid & 63;
    int q    = lane >> 4;
    int mc   = lane & 15;

    int n    = blockIdx.x;
    int swiz = (n & 7) * 200 + (n >> 3);  // co-locate same-f blocks per XCD
    int f    = swiz >> 4;
    int bt   = swiz & 15;
    int b0   = bt * 64 + wid * 16;        // this wave's first batch row

    const int* swrf = swr + f * NEST_;
    float* zw = zsh[wid];

    // ---- softmax in A-frag lanes: ws[m=mc][e=kk*32+q*8+j] ----
    float ex[4][8];
    float mx = -1e30f;
#pragma unroll
    for (int kk = 0; kk < 4; ++kk) {
        int4 r0 = *(const int4*)(swrf + kk * 32 + q * 8);
        int4 r1 = *(const int4*)(swrf + kk * 32 + q * 8 + 4);
        int rr[8] = { r0.x, r0.y, r0.z, r0.w, r1.x, r1.y, r1.z, r1.w };
#pragma unroll
        for (int j = 0; j < 8; ++j) {
            float v = w_t[rr[j] * B_ + b0 + mc];
            ex[kk][j] = v;
            mx = fmaxf(mx, v);
        }
    }
    mx = fmaxf(mx, __shfl_xor(mx, 16));
    mx = fmaxf(mx, __shfl_xor(mx, 32));
    float s = 0.f;
#pragma unroll
    for (int kk = 0; kk < 4; ++kk)
#pragma unroll
        for (int j = 0; j < 8; ++j) { ex[kk][j] = __expf(ex[kk][j] - mx); s += ex[kk][j]; }
    s += __shfl_xor(s, 16);
    s += __shfl_xor(s, 32);
    float inv = 1.f / s;

    bf16x8 afr[4];
#pragma unroll
    for (int kk = 0; kk < 4; ++kk)
#pragma unroll
        for (int j = 0; j < 8; ++j) afr[kk][j] = (bf16_t)(ex[kk][j] * inv);

    // ---- F-GEMM: all 8 n-tiles, K=128, B split hi/lo ----
    f32x4 accF[8];
#pragma unroll
    for (int nn = 0; nn < 8; ++nn) accF[nn] = (f32x4){0.f, 0.f, 0.f, 0.f};
    const bf16x8* EHf = (const bf16x8*)Eh;
    const bf16x8* ELf = (const bf16x8*)El;
#pragma unroll
    for (int kk = 0; kk < 4; ++kk) {
        size_t bi = (size_t)(f * 4 + kk) * 8;
#pragma unroll
        for (int nn = 0; nn < 8; ++nn) {
            bf16x8 bh = EHf[(bi + nn) * 64 + lane];
            bf16x8 bl = ELf[(bi + nn) * 64 + lane];
            accF[nn] = MFMA16(afr[kk], bh, accF[nn]);
            accF[nn] = MFMA16(afr[kk], bl, accF[nn]);
        }
    }

    // ---- LayerNorm 1 (wave-internal): rows q*4+reg ----
    float mu[4], rs[4];
#pragma unroll
    for (int reg = 0; reg < 4; ++reg) {
        float ps = 0.f, pq = 0.f;
#pragma unroll
        for (int nn = 0; nn < 8; ++nn) { float v = accF[nn][reg]; ps += v; pq += v * v; }
#pragma unroll
        for (int o = 1; o <= 8; o <<= 1) { ps += __shfl_xor(ps, o); pq += __shfl_xor(pq, o); }
        float m_ = ps * (1.f / NHID_);
        mu[reg] = m_;
        rs[reg] = rsqrtf(pq * (1.f / NHID_) - m_ * m_ + EPS_);
    }
    {
#pragma unroll
        for (int nn = 0; nn < 8; ++nn) {
            int c = nn * 16 + mc;
            float gv = ln1g[c], bv = ln1b[c];
#pragma unroll
            for (int reg = 0; reg < 4; ++reg)
                zw[(q * 4 + reg) * 132 + c] = (accF[nn][reg] - mu[reg]) * rs[reg] * gv + bv;
        }
    }

    // ---- lin1 GEMM: A from zw (single bf16), B = Wh/Wl ----
    bf16x8 a2[4];
#pragma unroll
    for (int kk = 0; kk < 4; ++kk) {
        int dwb = kk * 32 + q * 8;
        f32x4 u0 = *(const f32x4*)&zw[mc * 132 + dwb];
        f32x4 u1 = *(const f32x4*)&zw[mc * 132 + dwb + 4];
#pragma unroll
        for (int j = 0; j < 4; ++j) { a2[kk][j] = (bf16_t)u0[j]; a2[kk][4 + j] = (bf16_t)u1[j]; }
    }
    f32x4 accA[8];
#pragma unroll
    for (int nn = 0; nn < 8; ++nn) accA[nn] = (f32x4){0.f, 0.f, 0.f, 0.f};
    const bf16x8* WHf = (const bf16x8*)Wh;
    const bf16x8* WLf = (const bf16x8*)Wl;
#pragma unroll
    for (int kk = 0; kk < 4; ++kk) {
#pragma unroll
        for (int nn = 0; nn < 8; ++nn) {
            bf16x8 bh = WHf[(kk * 8 + nn) * 64 + lane];
            bf16x8 bl = WLf[(kk * 8 + nn) * 64 + lane];
            accA[nn] = MFMA16(a2[kk], bh, accA[nn]);
            accA[nn] = MFMA16(a2[kk], bl, accA[nn]);
        }
    }

    // ---- bias + ReLU + LayerNorm 2 (wave-internal) ----
#pragma unroll
    for (int nn = 0; nn < 8; ++nn) {
        float bv = lin1b[nn * 16 + mc];
#pragma unroll
        for (int reg = 0; reg < 4; ++reg)
            accA[nn][reg] = fmaxf(accA[nn][reg] + bv, 0.f);
    }
    float mu2[4], rs2[4];
#pragma unroll
    for (int reg = 0; reg < 4; ++reg) {
        float ps = 0.f, pq = 0.f;
#pragma unroll
        for (int nn = 0; nn < 8; ++nn) { float v = accA[nn][reg]; ps += v; pq += v * v; }
#pragma unroll
        for (int o = 1; o <= 8; o <<= 1) { ps += __shfl_xor(ps, o); pq += __shfl_xor(pq, o); }
        float m_ = ps * (1.f / NHID_);
        mu2[reg] = m_;
        rs2[reg] = rsqrtf(pq * (1.f / NHID_) - m_ * m_ + EPS_);
    }
    {
#pragma unroll
        for (int nn = 0; nn < 8; ++nn) {
            int c = nn * 16 + mc;
            float gv = ln2g[c], bv = ln2b[c];
#pragma unroll
            for (int reg = 0; reg < 4; ++reg)
                zw[(q * 4 + reg) * 132 + c] = (accA[nn][reg] - mu2[reg]) * rs2[reg] * gv + bv;
        }
    }

    // ---- lin2: 16x128 @ 128x16(padded), accumulate over forests ----
    f32x4 accO = {0.f, 0.f, 0.f, 0.f};
    const bf16x8* LHf = (const bf16x8*)L2h;
    const bf16x8* LLf = (const bf16x8*)L2l;
#pragma unroll
    for (int kk = 0; kk < 4; ++kk) {
        int dwb = kk * 32 + q * 8;
        f32x4 u0 = *(const f32x4*)&zw[mc * 132 + dwb];
        f32x4 u1 = *(const f32x4*)&zw[mc * 132 + dwb + 4];
        bf16x8 a3;
#pragma unroll
        for (int j = 0; j < 4; ++j) { a3[j] = (bf16_t)u0[j]; a3[4 + j] = (bf16_t)u1[j]; }
        accO = MFMA16(a3, LHf[kk * 64 + lane], accO);
        accO = MFMA16(a3, LLf[kk * 64 + lane], accO);
    }
    if (mc < NCLASS_) {
#pragma unroll
        for (int reg = 0; reg < 4; ++reg)
            atomicAdd(&acc[(b0 + q * 4 + reg) * NCLASS_ + mc], accO[reg]);
    }
}

// ---------------------------------------------------------------------------
// k_final: out = acc/NFOREST + lin2_b
// ---------------------------------------------------------------------------
__global__ __launch_bounds__(256) void k_final(
    const float* __restrict__ acc, const float* __restrict__ lin2b,
    float* __restrict__ out)
{
    int i = blockIdx.x * 256 + threadIdx.x;
    if (i < B_ * NCLASS_) {
        int c = i % NCLASS_;
        out[i] = acc[i] * (1.f / NFOREST_) + lin2b[c];
    }
}

// ---------------------------------------------------------------------------
extern "C" void kernel_launch(void* const* d_in, const int* in_sizes, int n_in,
                              void* d_out, int out_size, void* d_ws, size_t ws_size,
                              hipStream_t stream)
{
    const float* x     = (const float*)d_in[0];
    const float* w1    = (const float*)d_in[1];
    const float* b1    = (const float*)d_in[2];
    const int*   perm  = (const int*)  d_in[3];
    const float* gn1g  = (const float*)d_in[4];
    const float* gn1b  = (const float*)d_in[5];
    const float* w2a   = (const float*)d_in[6];
    const float* b2a   = (const float*)d_in[7];
    const float* gn2g  = (const float*)d_in[8];
    const float* gn2b  = (const float*)d_in[9];
    const float* w2b   = (const float*)d_in[10];
    const float* b2b   = (const float*)d_in[11];
    const float* E     = (const float*)d_in[12];
    const int*   swr   = (const int*)  d_in[13];
    const float* ln1g  = (const float*)d_in[14];
    const float* ln1b  = (const float*)d_in[15];
    const float* lin1w = (const float*)d_in[16];
    const float* lin1b = (const float*)d_in[17];
    const float* ln2g  = (const float*)d_in[18];
    const float* ln2b  = (const float*)d_in[19];
    const float* lin2w = (const float*)d_in[20];
    const float* lin2b = (const float*)d_in[21];

    char* base = (char*)d_ws;
    float*  w_t  = (float*)base;                                    // 4 MB
    float*  accp = (float*)(base + 4u * 1024 * 1024);               // 40 KB
    float*  x_t  = (float*)(base + 4u * 1024 * 1024 + 64 * 1024);   // 256 KB
    bf16_t* Eh   = (bf16_t*)(base + 4u * 1024 * 1024 + 64 * 1024 + 256 * 1024);
    bf16_t* El   = Eh  + (size_t)EG_FRAGS * 8;
    bf16_t* Wh   = El  + (size_t)EG_FRAGS * 8;
    bf16_t* Wl   = Wh  + (size_t)W1_FRAGS * 8;
    bf16_t* L2h  = Wl  + (size_t)W1_FRAGS * 8;
    bf16_t* L2l  = L2h + (size_t)L2_FRAGS * 8;

    k_prep<<<1105, 256, 0, stream>>>(E, swr, lin1w, lin2w, x,
                                     Eh, El, Wh, Wl, L2h, L2l, x_t, accp);

    k_rodt<<<NRODT_, 256, 0, stream>>>(
        x_t, w1, b1, perm, gn1g, gn1b, w2a, b2a, gn2g, gn2b, w2b, b2b, w_t);

    k_forest<<<NFOREST_ * 16, 256, 0, stream>>>(
        w_t, swr, Eh, El, Wh, Wl, L2h, L2l,
        ln1g, ln1b, lin1b, ln2g, ln2b, accp);

    k_final<<<(B_ * NCLASS_ + 255) / 256, 256, 0, stream>>>(
        accp, lin2b, (float*)d_out);
}